// Round 4
// baseline (4893.385 us; speedup 1.0000x reference)
//
#include <hip/hip_runtime.h>
#include <stdint.h>

#define DEVI __device__ __forceinline__

#define S_TOT 261888
#define NIMG  2
#define SCLD  4.135166556742356   // log(1000/16)

// ---------------- constant tables (all compile-time) ----------------
__constant__ int    c_S[5]    = {196608, 49152, 12288, 3072, 768};
__constant__ int    c_loff[5] = {0, 196608, 245760, 258048, 261120};
__constant__ int    c_K[5]    = {1000, 1000, 1000, 1000, 768};
__constant__ int    c_Wl[5]   = {256, 128, 64, 32, 16};
__constant__ int    c_str[5]  = {4, 8, 16, 32, 64};
__constant__ double c_sz[5]   = {32.0, 64.0, 128.0, 256.0, 512.0};
__constant__ double c_rat[3]  = {0.5, 1.0, 2.0};
// merged conv block decode: tiles are 16x16 px; per-level block counts {256,64,16,4,1}
__constant__ int    c_boff[6] = {0, 256, 320, 336, 340, 341};
__constant__ int    c_Hl[5]   = {256, 128, 64, 32, 16};

// order-preserving float<->uint key (ascending key == ascending float)
DEVI unsigned key_of(float f) {
  unsigned u = __float_as_uint(f);
  return (u & 0x80000000u) ? ~u : (u | 0x80000000u);
}
DEVI float key_dec(unsigned k) {
  unsigned u = (k & 0x80000000u) ? (k & 0x7fffffffu) : ~k;
  return __uint_as_float(u);
}

// ---------------- kernel 1: weight relayout for LDS-broadcast consumption ----------------
// wT3[(pass*32+chunk)*9216 + cc*1152 + g*144 + j*16 + i] = w[co][ci*9+j]
// with co = pass*128 + g*16 + i, ci = chunk*8 + cc.  Each (pass,chunk) region is a flat
// 9216-dword run -> coalesced float4 copy into LDS; per (cc,g) a 144-dword run for b128 reads.
__global__ void transpose_w(const float* __restrict__ w, float* __restrict__ wT3) {
  int k  = blockIdx.x;   // 0..2303  (ci*9 + j)
  int co = threadIdx.x;  // 0..255
  int ci = k / 9, j = k - ci * 9;
  int chunk = ci >> 3, cc = ci & 7;
  int pass = co >> 7, g = (co >> 4) & 7, i = co & 15;
  wT3[((size_t)(pass * 32 + chunk)) * 9216 + cc * 1152 + g * 144 + j * 16 + i] =
      w[co * 2304 + k];
}

// ---------------- kernel 2: fused conv3x3+bias+relu then 1x1 obj/delta, ALL levels in one grid ----
// block = 512 thr (8 waves). tile = 16x16 px, lane owns 4 px (rows p,p+4,p+8,p+12).
// 2 cout passes: pass p, wave w own co = 128p+16w .. +15. Weights staged per 8-ci chunk into
// LDS; each wave reads its group's 144 dwords per ci via uniform-address ds_read_b128
// (broadcast, conflict-free). Pass0 stores raw 1x1 partial sums (channel order 0..127
// sequential) into logits/deltas; pass1 continues the SAME sequential accumulation chain
// (128..255) and adds bias -> bit-identical to a 0..255 sequential sum.
__global__ __launch_bounds__(512, 4) void conv_fused(
    const float* __restrict__ x0, const float* __restrict__ x1,
    const float* __restrict__ x2, const float* __restrict__ x3,
    const float* __restrict__ x4,
    const float* __restrict__ wT3,
    const float* __restrict__ cb, const float* __restrict__ ow,
    const float* __restrict__ ob, const float* __restrict__ dwt,
    const float* __restrict__ db, float* __restrict__ logits,
    float* __restrict__ deltas)
{
  __shared__ float lds[11808];  // 47.2 KB: patch [0,2592) + weights [2592,11808); reduce reuses [0,7680)
  float* const wlds = lds + 2592;
  const int tid = threadIdx.x;
  const int n = blockIdx.y;
  const int b = blockIdx.x;
  int l = 0;
#pragma unroll
  for (int q = 1; q < 5; ++q) if (b >= c_boff[q]) l = q;
  const int t = b - c_boff[l];
  const int H = c_Hl[l], W = H;
  const int tilesx = 16 >> l;
  const int tx = t & (tilesx - 1), ty = t >> (4 - l);
  const int px0 = tx << 4, py0 = ty << 4;
  const int loff = c_loff[l];
  const float* xin = (l == 0) ? x0 : (l == 1) ? x1 : (l == 2) ? x2 : (l == 3) ? x3 : x4;
  xin += (size_t)n * 256 * H * W;

  const int lane = tid & 63, wv = tid >> 6;
  const int px = lane & 15, p = lane >> 4;   // p 0..3; lane owns rows p,p+4,p+8,p+12

  for (int pass = 0; pass < 2; ++pass) {
    const int g = wv;                 // cout group within pass (wave-uniform)
    const int co0 = (pass << 7) + (g << 4);

    float acc[4][16];
#pragma unroll
    for (int k = 0; k < 4; ++k)
#pragma unroll
      for (int i = 0; i < 16; ++i) acc[k][i] = 0.f;

    for (int ch = 0; ch < 32; ++ch) {        // 32 chunks of 8 input channels
      const int ci0 = ch << 3;
      __syncthreads();
      // stage input patch 8ci x 18 x 18 (zero-padded halo)
      for (int tt = tid; tt < 2592; tt += 512) {
        int ci = tt / 324, rem = tt - ci * 324;
        int ry = rem / 18, rx = rem - ry * 18;
        int gy = py0 + ry - 1, gx = px0 + rx - 1;
        float v = 0.f;
        if (gy >= 0 && gy < H && gx >= 0 && gx < W)
          v = xin[((size_t)(ci0 + ci) * H + gy) * W + gx];
        lds[tt] = v;
      }
      // stage this chunk's weights: flat 9216 dwords, coalesced float4
      {
        const float4* wg = (const float4*)(wT3 + ((size_t)(pass * 32 + ch)) * 9216);
        float4* wl = (float4*)wlds;
        for (int tt = tid; tt < 2304; tt += 512) wl[tt] = wg[tt];
      }
      __syncthreads();
#pragma unroll 1
      for (int cc = 0; cc < 8; ++cc) {
        const int pb = cc * 324 + p * 18 + px;          // patch row (p+4k+ky), col (px+kx)
        const float* wr = wlds + cc * 1152 + g * 144;   // wave-uniform -> broadcast ds_read
#pragma unroll
        for (int ky = 0; ky < 3; ++ky) {
          float pvk[4][3];
#pragma unroll
          for (int k = 0; k < 4; ++k)
#pragma unroll
            for (int kx = 0; kx < 3; ++kx)
              pvk[k][kx] = lds[pb + ((k << 2) + ky) * 18 + kx];
#pragma unroll
          for (int kx = 0; kx < 3; ++kx) {
            const float4 w0 = *(const float4*)(wr + (ky * 3 + kx) * 16 + 0);
            const float4 w1 = *(const float4*)(wr + (ky * 3 + kx) * 16 + 4);
            const float4 w2 = *(const float4*)(wr + (ky * 3 + kx) * 16 + 8);
            const float4 w3 = *(const float4*)(wr + (ky * 3 + kx) * 16 + 12);
#pragma unroll
            for (int k = 0; k < 4; ++k) {
              acc[k][0]  = fmaf(w0.x, pvk[k][kx], acc[k][0]);
              acc[k][1]  = fmaf(w0.y, pvk[k][kx], acc[k][1]);
              acc[k][2]  = fmaf(w0.z, pvk[k][kx], acc[k][2]);
              acc[k][3]  = fmaf(w0.w, pvk[k][kx], acc[k][3]);
              acc[k][4]  = fmaf(w1.x, pvk[k][kx], acc[k][4]);
              acc[k][5]  = fmaf(w1.y, pvk[k][kx], acc[k][5]);
              acc[k][6]  = fmaf(w1.z, pvk[k][kx], acc[k][6]);
              acc[k][7]  = fmaf(w1.w, pvk[k][kx], acc[k][7]);
              acc[k][8]  = fmaf(w2.x, pvk[k][kx], acc[k][8]);
              acc[k][9]  = fmaf(w2.y, pvk[k][kx], acc[k][9]);
              acc[k][10] = fmaf(w2.z, pvk[k][kx], acc[k][10]);
              acc[k][11] = fmaf(w2.w, pvk[k][kx], acc[k][11]);
              acc[k][12] = fmaf(w3.x, pvk[k][kx], acc[k][12]);
              acc[k][13] = fmaf(w3.y, pvk[k][kx], acc[k][13]);
              acc[k][14] = fmaf(w3.z, pvk[k][kx], acc[k][14]);
              acc[k][15] = fmaf(w3.w, pvk[k][kx], acc[k][15]);
            }
          }
        }
      }
    }

    // epilogue for this pass: bias+relu, partial 1x1 (3 obj + 12 delta) over these 16 ch,
    // cross-wave reduce (wave-ascending = channel-ascending), chain through global partials.
    // FULLY UNROLLED k (compile-time acc indexing -> no scratch spill).
#pragma unroll
    for (int k = 0; k < 4; ++k) {
      float part[15];
#pragma unroll
      for (int f = 0; f < 15; ++f) part[f] = 0.f;
#pragma unroll
      for (int i = 0; i < 16; ++i) {
        float tv = fmaxf(acc[k][i] + cb[co0 + i], 0.f);
#pragma unroll
        for (int f = 0; f < 3; ++f)  part[f]     = fmaf(tv, ow[f * 256 + co0 + i],  part[f]);
#pragma unroll
        for (int f = 0; f < 12; ++f) part[3 + f] = fmaf(tv, dwt[f * 256 + co0 + i], part[3 + f]);
      }
      __syncthreads();
#pragma unroll
      for (int f = 0; f < 15; ++f) lds[wv * 960 + f * 64 + lane] = part[f];
      __syncthreads();
      for (int tt = tid; tt < 960; tt += 512) {
        int f = tt >> 6, pp = tt & 63;
        int gx = px0 + (pp & 15), gy = py0 + (pp >> 4) + (k << 2);
        int cell = gy * W + gx;
        size_t adr;
        float bias;
        if (f < 3) {
          adr = (size_t)n * S_TOT + loff + cell * 3 + f;
          bias = ob[f];
        } else {
          int chn = f - 3, a = chn >> 2, c = chn & 3;
          adr = (((size_t)n * S_TOT + loff + cell * 3 + a) << 2) + c;
          bias = db[chn];
        }
        float* dst = (f < 3) ? logits : deltas;
        float s = (pass == 0) ? 0.f : dst[adr];
#pragma unroll
        for (int w2 = 0; w2 < 8; ++w2) s += lds[w2 * 960 + tt];   // fixed order: deterministic
        dst[adr] = (pass == 0) ? s : (s + bias);
      }
    }
  }
}

// ---------------- kernel 3: exact top-K + box decode per (image, level) ----------------
__global__ __launch_bounds__(1024) void topk_kernel(
    const float* __restrict__ logits, const float* __restrict__ deltas,
    float* __restrict__ selscore, float* __restrict__ selbox,
    unsigned* __restrict__ selvalid)
{
  const int tid = threadIdx.x;
  const int nl = blockIdx.x, n = nl / 5, l = nl % 5;
  const int Sl = c_S[l], loff = c_loff[l], Kl = c_K[l], Wl = c_Wl[l], strl = c_str[l];
  const float* sc = logits + (size_t)n * S_TOT + loff;

  __shared__ unsigned hist[256];
  __shared__ unsigned sh_prefix, sh_need, s_base, s_cb;
  __shared__ unsigned waveTot[16], waveOff[16];
  __shared__ unsigned long long sortbuf[1024];

  // phase 1: 4-pass radix histogram -> exact Kl-th largest key
  unsigned prefix = 0, need = (unsigned)Kl;
  for (int p = 0; p < 4; ++p) {
    for (int i = tid; i < 256; i += 1024) hist[i] = 0;
    __syncthreads();
    const int shift = 24 - p * 8;
    for (int i = tid; i < Sl; i += 1024) {
      unsigned k = key_of(sc[i]);
      if (p == 0 || (k >> (shift + 8)) == prefix)
        atomicAdd(&hist[(k >> shift) & 255u], 1u);
    }
    __syncthreads();
    if (tid == 0) {
      unsigned cum = 0;
      for (int b = 255; b >= 0; --b) {
        unsigned c = hist[b];
        if (cum + c >= need) { sh_prefix = (prefix << 8) | (unsigned)b; sh_need = need - cum; break; }
        cum += c;
      }
    }
    __syncthreads();
    prefix = sh_prefix; need = sh_need;
    __syncthreads();
  }
  const unsigned Tkey = prefix;

  // phase 2: stable compaction (strictly-greater, then equals capped) -> exactly Kl entries
  if (tid == 0) s_base = 0;
  __syncthreads();
  for (int pass = 0; pass < 2; ++pass) {
    for (int st = 0; st < Sl; st += 1024) {
      const int i = st + tid;
      bool flag = false; unsigned k = 0;
      if (i < Sl) {
        k = key_of(sc[i]);
        flag = (pass == 0) ? (k > Tkey) : (k == Tkey);
      }
      unsigned long long m = __ballot(flag);
      const int lane = tid & 63, w = tid >> 6;
      unsigned mypre = (unsigned)__popcll(m & ((1ull << lane) - 1ull));
      if (lane == 0) waveTot[w] = (unsigned)__popcll(m);
      __syncthreads();
      if (tid == 0) {
        unsigned ss = 0;
        for (int q = 0; q < 16; ++q) { waveOff[q] = ss; ss += waveTot[q]; }
        s_cb = s_base; s_base += ss;
      }
      __syncthreads();
      if (flag) {
        unsigned pos = s_cb + waveOff[w] + mypre;
        if (pos < (unsigned)Kl)
          sortbuf[pos] = (((unsigned long long)k) << 32) |
                         (unsigned long long)(0xFFFFFFFFu - (unsigned)i);
      }
      __syncthreads();
    }
  }
  if (tid >= Kl) sortbuf[tid] = (unsigned long long)(0xFFFFFFFFu - (unsigned)tid); // pads: key 0
  __syncthreads();

  // phase 3: bitonic sort of 1024 u64, descending (key desc, idx asc via ~idx)
  for (int k2 = 2; k2 <= 1024; k2 <<= 1) {
    for (int j = k2 >> 1; j > 0; j >>= 1) {
      const int i = tid, ixj = i ^ j;
      if (ixj > i) {
        unsigned long long a = sortbuf[i], b = sortbuf[ixj];
        const bool desc = (i & k2) == 0;
        if (desc ? (a < b) : (a > b)) { sortbuf[i] = b; sortbuf[ixj] = a; }
      }
      __syncthreads();
    }
  }

  // phase 4: decode boxes (anchors in f64 to bit-match np reference)
  const int r = tid;
  const int o = nl * 1024 + r;
  if (r < Kl) {
    unsigned long long v = sortbuf[r];
    unsigned k = (unsigned)(v >> 32);
    unsigned ai = 0xFFFFFFFFu - (unsigned)(v & 0xFFFFFFFFull);
    float score = key_dec(k);
    int cell = (int)(ai / 3u), a = (int)(ai % 3u);
    int xg = cell % Wl, yg = cell / Wl;
    double rr = c_rat[a], sz = c_sz[l];
    double wsd = sqrt(sz * sz / rr);
    double hw = 0.5 * wsd, hh = 0.5 * wsd * rr;
    double xs = (double)(xg * strl), ys = (double)(yg * strl);
    float a0 = (float)(xs - hw), a1 = (float)(ys - hh);
    float a2 = (float)(xs + hw), a3 = (float)(ys + hh);
    const float* dp = deltas + (((size_t)n * S_TOT + loff + ai) << 2);
    float dx = dp[0], dy = dp[1], dw_ = dp[2], dh_ = dp[3];
    float aw = a2 - a0, ah = a3 - a1;
    float cx = a0 + 0.5f * aw, cy = a1 + 0.5f * ah;
    dw_ = fminf(dw_, (float)SCLD); dh_ = fminf(dh_, (float)SCLD);
    float pcx = dx * aw + cx, pcy = dy * ah + cy;
    float pw = expf(dw_) * aw, ph = expf(dh_) * ah;
    float b0 = fminf(fmaxf(pcx - 0.5f * pw, 0.f), 1024.f);
    float b1 = fminf(fmaxf(pcy - 0.5f * ph, 0.f), 1024.f);
    float b2 = fminf(fmaxf(pcx + 0.5f * pw, 0.f), 1024.f);
    float b3 = fminf(fmaxf(pcy + 0.5f * ph, 0.f), 1024.f);
    unsigned valid = ((b2 - b0) > 0.f && (b3 - b1) > 0.f) ? 1u : 0u;
    selscore[o] = score;
    selbox[o * 4 + 0] = b0; selbox[o * 4 + 1] = b1;
    selbox[o * 4 + 2] = b2; selbox[o * 4 + 3] = b3;
    selvalid[o] = valid;
  } else {
    selscore[o] = -1e9f;
    selbox[o * 4 + 0] = 0.f; selbox[o * 4 + 1] = 0.f;
    selbox[o * 4 + 2] = 0.f; selbox[o * 4 + 3] = 0.f;
    selvalid[o] = 0u;
  }
}

// ---------------- kernel 4: NMS suppression bitmask matrix ----------------
__global__ __launch_bounds__(256) void nms_sup(
    const float* __restrict__ selbox, unsigned long long* __restrict__ sup)
{
  int gid = blockIdx.x * 256 + threadIdx.x;  // 10 * 1024 * 16
  int w = gid & 15, i = (gid >> 4) & 1023, nl = gid >> 14;
  if (nl >= 10) return;
  int l = nl % 5, Kl = c_K[l];
  unsigned long long bits = 0;
  if (i < Kl) {
    const float* bi = selbox + (size_t)(nl * 1024 + i) * 4;
    float x0 = bi[0], y0 = bi[1], x1 = bi[2], y1 = bi[3];
    float ar = (x1 - x0) * (y1 - y0);
    int jlo = w * 64; if (jlo < i + 1) jlo = i + 1;
    int jhi = w * 64 + 64; if (jhi > Kl) jhi = Kl;
    for (int j = jlo; j < jhi; ++j) {
      const float* bj = selbox + (size_t)(nl * 1024 + j) * 4;
      float u0 = fmaxf(x0, bj[0]), v0 = fmaxf(y0, bj[1]);
      float u1 = fminf(x1, bj[2]), v1 = fminf(y1, bj[3]);
      float iw = fmaxf(u1 - u0, 0.f), ih = fmaxf(v1 - v0, 0.f);
      float inter = iw * ih;
      float aj = (bj[2] - bj[0]) * (bj[3] - bj[1]);
      float iou = inter / fmaxf(ar + aj - inter, 1e-9f);
      if (iou > 0.7f) bits |= 1ull << (j - w * 64);
    }
  }
  sup[(size_t)(nl * 1024 + i) * 16 + w] = bits;
}

// ---------------- kernel 5: sequential greedy NMS reduce (1 wave / (n,l)) ----------------
__global__ __launch_bounds__(64) void nms_reduce(
    const unsigned* __restrict__ selvalid, const unsigned long long* __restrict__ sup,
    const float* __restrict__ selscore, float* __restrict__ scnms)
{
  const int nl = blockIdx.x, tid = threadIdx.x;
  const int l = nl % 5, Kl = c_K[l];
  unsigned long long keep = 0;
  if (tid < 16) {
    for (int t = 0; t < 64; ++t) {
      int r = tid * 64 + t;
      if (r < Kl && selvalid[nl * 1024 + r]) keep |= 1ull << t;
    }
  }
  const unsigned long long* srow = sup + (size_t)nl * 1024 * 16;
  unsigned long long rowA = (tid < 16) ? srow[(size_t)0 * 16 + tid] : 0;
  unsigned long long rowB = (tid < 16 && Kl > 1) ? srow[(size_t)1 * 16 + tid] : 0;
  for (int i = 0; i < Kl; i += 2) {   // Kl is even (1000 / 768)
    unsigned long long kw = __shfl(keep, i >> 6);
    unsigned long long cur = rowA;
    rowA = (tid < 16 && i + 2 < Kl) ? srow[(size_t)(i + 2) * 16 + tid] : 0;
    if (((kw >> (i & 63)) & 1ull) && tid < 16) keep &= ~cur;
    kw = __shfl(keep, (i + 1) >> 6);
    cur = rowB;
    rowB = (tid < 16 && i + 3 < Kl) ? srow[(size_t)(i + 3) * 16 + tid] : 0;
    if (((kw >> ((i + 1) & 63)) & 1ull) && tid < 16) keep &= ~cur;
  }
  for (int r = tid; r < 1024; r += 64) {
    unsigned long long wv = __shfl(keep, r >> 6);
    bool kp = (r < Kl) && ((wv >> (r & 63)) & 1ull);
    scnms[nl * 1024 + r] = kp ? selscore[nl * 1024 + r] : -1e9f;
  }
}

// ---------------- kernel 6: final per-image top-1000 of 4768 + output ----------------
DEVI float cand_score(const float* scnms, int n, int g) {
  int l = g / 1000;               // g < 4768 -> l in [0,4]
  int r = g - l * 1000;
  return scnms[((n * 5 + l) << 10) + r];
}

__global__ __launch_bounds__(1024) void final_topk(
    const float* __restrict__ scnms, const float* __restrict__ selbox,
    float* __restrict__ out)
{
  const int tid = threadIdx.x;
  const int n = blockIdx.x;
  const int S = 4768;

  __shared__ unsigned hist[256];
  __shared__ unsigned sh_prefix, sh_need, s_base, s_cb;
  __shared__ unsigned waveTot[16], waveOff[16];
  __shared__ unsigned long long sortbuf[1024];

  unsigned prefix = 0, need = 1000;
  for (int p = 0; p < 4; ++p) {
    for (int i = tid; i < 256; i += 1024) hist[i] = 0;
    __syncthreads();
    const int shift = 24 - p * 8;
    for (int i = tid; i < S; i += 1024) {
      unsigned k = key_of(cand_score(scnms, n, i));
      if (p == 0 || (k >> (shift + 8)) == prefix)
        atomicAdd(&hist[(k >> shift) & 255u], 1u);
    }
    __syncthreads();
    if (tid == 0) {
      unsigned cum = 0;
      for (int b = 255; b >= 0; --b) {
        unsigned c = hist[b];
        if (cum + c >= need) { sh_prefix = (prefix << 8) | (unsigned)b; sh_need = need - cum; break; }
        cum += c;
      }
    }
    __syncthreads();
    prefix = sh_prefix; need = sh_need;
    __syncthreads();
  }
  const unsigned Tkey = prefix;

  if (tid == 0) s_base = 0;
  __syncthreads();
  for (int pass = 0; pass < 2; ++pass) {
    for (int st = 0; st < S; st += 1024) {
      const int i = st + tid;
      bool flag = false; unsigned k = 0;
      if (i < S) {
        k = key_of(cand_score(scnms, n, i));
        flag = (pass == 0) ? (k > Tkey) : (k == Tkey);
      }
      unsigned long long m = __ballot(flag);
      const int lane = tid & 63, w = tid >> 6;
      unsigned mypre = (unsigned)__popcll(m & ((1ull << lane) - 1ull));
      if (lane == 0) waveTot[w] = (unsigned)__popcll(m);
      __syncthreads();
      if (tid == 0) {
        unsigned ss = 0;
        for (int q = 0; q < 16; ++q) { waveOff[q] = ss; ss += waveTot[q]; }
        s_cb = s_base; s_base += ss;
      }
      __syncthreads();
      if (flag) {
        unsigned pos = s_cb + waveOff[w] + mypre;
        if (pos < 1000u)
          sortbuf[pos] = (((unsigned long long)k) << 32) |
                         (unsigned long long)(0xFFFFFFFFu - (unsigned)i);
      }
      __syncthreads();
    }
  }
  if (tid >= 1000) sortbuf[tid] = (unsigned long long)(0xFFFFFFFFu - (unsigned)tid);
  __syncthreads();

  for (int k2 = 2; k2 <= 1024; k2 <<= 1) {
    for (int j = k2 >> 1; j > 0; j >>= 1) {
      const int i = tid, ixj = i ^ j;
      if (ixj > i) {
        unsigned long long a = sortbuf[i], b = sortbuf[ixj];
        const bool desc = (i & k2) == 0;
        if (desc ? (a < b) : (a > b)) { sortbuf[i] = b; sortbuf[ixj] = a; }
      }
      __syncthreads();
    }
  }

  if (tid < 1000) {
    unsigned long long v = sortbuf[tid];
    unsigned k = (unsigned)(v >> 32);
    int g = (int)(0xFFFFFFFFu - (unsigned)(v & 0xFFFFFFFFull));
    int l = g / 1000, r = g - l * 1000;
    const float* b = selbox + ((size_t)((n * 5 + l) * 1024 + r)) * 4;
    size_t ob_ = ((size_t)n * 1000 + tid) * 4;
    out[ob_ + 0] = b[0]; out[ob_ + 1] = b[1];
    out[ob_ + 2] = b[2]; out[ob_ + 3] = b[3];
    out[8000 + n * 1000 + tid] = key_dec(k);
  }
}

// ---------------- host launcher ----------------
extern "C" void kernel_launch(void* const* d_in, const int* in_sizes, int n_in,
                              void* d_out, int out_size, void* d_ws, size_t ws_size,
                              hipStream_t stream)
{
  const float* feats[5];
  for (int i = 0; i < 5; ++i) feats[i] = (const float*)d_in[i];
  const float* conv_w  = (const float*)d_in[5];
  const float* conv_b  = (const float*)d_in[6];
  const float* obj_w   = (const float*)d_in[7];
  const float* obj_b   = (const float*)d_in[8];
  const float* delta_w = (const float*)d_in[9];
  const float* delta_b = (const float*)d_in[10];

  char* wsp = (char*)d_ws;
  float* wT3      = (float*)wsp;  wsp += (size_t)2304 * 256 * 4;     // 2.36 MB
  float* logits   = (float*)wsp;  wsp += (size_t)NIMG * S_TOT * 4;   // 2.10 MB
  float* deltas   = (float*)wsp;  wsp += (size_t)NIMG * S_TOT * 16;  // 8.38 MB
  float* selscore = (float*)wsp;  wsp += (size_t)10 * 1024 * 4;
  float* selbox   = (float*)wsp;  wsp += (size_t)10 * 1024 * 16;
  unsigned* selvalid = (unsigned*)wsp; wsp += (size_t)10 * 1024 * 4;
  float* scnms    = (float*)wsp;  wsp += (size_t)10 * 1024 * 4;
  unsigned long long* sup = (unsigned long long*)wsp;
  wsp += (size_t)10 * 1024 * 16 * 8;                                 // 1.31 MB

  transpose_w<<<dim3(2304), dim3(256), 0, stream>>>(conv_w, wT3);

  conv_fused<<<dim3(341, NIMG), dim3(512), 0, stream>>>(
      feats[0], feats[1], feats[2], feats[3], feats[4],
      wT3, conv_b, obj_w, obj_b, delta_w, delta_b, logits, deltas);

  topk_kernel<<<dim3(10), dim3(1024), 0, stream>>>(logits, deltas,
                                                   selscore, selbox, selvalid);
  nms_sup<<<dim3(640), dim3(256), 0, stream>>>(selbox, sup);
  nms_reduce<<<dim3(10), dim3(64), 0, stream>>>(selvalid, sup, selscore, scnms);
  final_topk<<<dim3(NIMG), dim3(1024), 0, stream>>>(scnms, selbox, (float*)d_out);
}

// Round 5
// 3694.835 us; speedup vs baseline: 1.3244x; 1.3244x over previous
//
#include <hip/hip_runtime.h>
#include <stdint.h>

#define DEVI __device__ __forceinline__

#define S_TOT 261888
#define NIMG  2
#define SCLD  4.135166556742356   // log(1000/16)

// ---------------- constant tables (all compile-time) ----------------
__constant__ int    c_S[5]    = {196608, 49152, 12288, 3072, 768};
__constant__ int    c_loff[5] = {0, 196608, 245760, 258048, 261120};
__constant__ int    c_K[5]    = {1000, 1000, 1000, 1000, 768};
__constant__ int    c_Wl[5]   = {256, 128, 64, 32, 16};
__constant__ int    c_str[5]  = {4, 8, 16, 32, 64};
__constant__ double c_sz[5]   = {32.0, 64.0, 128.0, 256.0, 512.0};
__constant__ double c_rat[3]  = {0.5, 1.0, 2.0};
// merged conv block decode: tiles are 16x8 px; per-level block counts {512,128,32,8,2}
__constant__ int    c_boff[6] = {0, 512, 640, 672, 680, 682};
__constant__ int    c_Hl[5]   = {256, 128, 64, 32, 16};

// order-preserving float<->uint key (ascending key == ascending float)
DEVI unsigned key_of(float f) {
  unsigned u = __float_as_uint(f);
  return (u & 0x80000000u) ? ~u : (u | 0x80000000u);
}
DEVI float key_dec(unsigned k) {
  unsigned u = (k & 0x80000000u) ? (k & 0x7fffffffu) : ~k;
  return __uint_as_float(u);
}

// ---------------- kernel 1: weight relayout for LDS-broadcast consumption ----------------
// wT3[chunk*18432 + cc*2304 + g*288 + j*32 + i] = w[co][ci*9+j]
// with co = g*32+i (g = wave, i = cout-in-wave), ci = chunk*8+cc.
// Each chunk is a flat 18432-dword run -> coalesced float4 staging into LDS;
// per (cc,g) a contiguous 288-dword run -> uniform-address ds_read_b128 broadcast.
__global__ void transpose_w(const float* __restrict__ w, float* __restrict__ wT3) {
  int k  = blockIdx.x;   // 0..2303  (ci*9 + j)
  int co = threadIdx.x;  // 0..255
  int ci = k / 9, j = k - ci * 9;
  int chunk = ci >> 3, cc = ci & 7;
  int g = co >> 5, i = co & 31;
  wT3[(size_t)chunk * 18432 + cc * 2304 + g * 288 + j * 32 + i] = w[co * 2304 + k];
}

// ---------------- kernel 2: fused conv3x3+bias+relu then 1x1 obj/delta, ALL levels in one grid ----
// block = 512 thr (8 waves). tile = 16x8 px, lane owns 2 px (rows p, p+4); wave w owns
// cout [32w, 32w+32) — SINGLE pass (R2-proven register shape, no spill).
// Weights per 8-ci chunk staged to LDS, read via wave-uniform ds_read_b128 (broadcast).
// FMA order per accumulator: ci ascending, tap (ky,kx) ascending — bit-identical to ref.
__global__ __launch_bounds__(512, 4) void conv_fused(
    const float* __restrict__ x0, const float* __restrict__ x1,
    const float* __restrict__ x2, const float* __restrict__ x3,
    const float* __restrict__ x4,
    const float* __restrict__ wT3,
    const float* __restrict__ cb, const float* __restrict__ ow,
    const float* __restrict__ ob, const float* __restrict__ dwt,
    const float* __restrict__ db, float* __restrict__ logits,
    float* __restrict__ deltas)
{
  __shared__ float lds[19872];  // 79.5 KB: patch [0,1440) + weights [1440,19872); reduce aliases [0,7680)
  float* const wlds = lds + 1440;
  const int tid = threadIdx.x;
  const int n = blockIdx.y;
  const int b = blockIdx.x;
  int l = 0;
#pragma unroll
  for (int q = 1; q < 5; ++q) if (b >= c_boff[q]) l = q;
  const int t = b - c_boff[l];
  const int H = c_Hl[l], W = H;
  const int tilesx = 16 >> l;
  const int tx = t & (tilesx - 1), ty = t >> (4 - l);
  const int px0 = tx << 4, py0 = ty << 3;
  const int loff = c_loff[l];
  const float* xin = (l == 0) ? x0 : (l == 1) ? x1 : (l == 2) ? x2 : (l == 3) ? x3 : x4;
  xin += (size_t)n * 256 * H * W;

  const int lane = tid & 63, wv = tid >> 6;
  const int px = lane & 15, p = lane >> 4;   // p 0..3; lane owns rows p and p+4

  float a0[32], a1[32];
#pragma unroll
  for (int i = 0; i < 32; ++i) { a0[i] = 0.f; a1[i] = 0.f; }

  for (int ch = 0; ch < 32; ++ch) {          // 32 chunks of 8 input channels
    const int ci0 = ch << 3;
    __syncthreads();
    // stage input patch 8ci x 10 x 18 (zero-padded halo): 1440 floats
    for (int tt = tid; tt < 1440; tt += 512) {
      int ci = tt / 180, rem = tt - ci * 180;
      int ry = rem / 18, rx = rem - ry * 18;
      int gy = py0 + ry - 1, gx = px0 + rx - 1;
      float v = 0.f;
      if (gy >= 0 && gy < H && gx >= 0 && gx < W)
        v = xin[((size_t)(ci0 + ci) * H + gy) * W + gx];
      lds[tt] = v;
    }
    // stage this chunk's weights: flat 18432 dwords, coalesced float4
    {
      const float4* wg = (const float4*)(wT3 + (size_t)ch * 18432);
      float4* wl = (float4*)wlds;
      for (int tt = tid; tt < 4608; tt += 512) wl[tt] = wg[tt];
    }
    __syncthreads();
#pragma unroll 1
    for (int cc = 0; cc < 8; ++cc) {
      const float* wr = wlds + cc * 2304 + wv * 288;   // wave-uniform base -> broadcast reads
      const int pb = cc * 180 + p * 18 + px;
#pragma unroll 1
      for (int ky = 0; ky < 3; ++ky) {
        const int rb = pb + ky * 18;
        // 6 patch values: rows (p+ky) and (p+4+ky), cols px..px+2  (ds_read2_b32 pairs)
        const float q00 = lds[rb + 0],  q01 = lds[rb + 1],  q02 = lds[rb + 2];
        const float q10 = lds[rb + 72], q11 = lds[rb + 73], q12 = lds[rb + 74];
        const float* wk = wr + ky * 96;
#pragma unroll
        for (int kx = 0; kx < 3; ++kx) {
          const float pv0 = (kx == 0) ? q00 : (kx == 1) ? q01 : q02;
          const float pv1 = (kx == 0) ? q10 : (kx == 1) ? q11 : q12;
          const float* wt = wk + kx * 32;
#pragma unroll
          for (int iq = 0; iq < 8; ++iq) {
            const float4 wq = *(const float4*)(wt + (iq << 2));
            a0[iq * 4 + 0] = fmaf(wq.x, pv0, a0[iq * 4 + 0]);
            a0[iq * 4 + 1] = fmaf(wq.y, pv0, a0[iq * 4 + 1]);
            a0[iq * 4 + 2] = fmaf(wq.z, pv0, a0[iq * 4 + 2]);
            a0[iq * 4 + 3] = fmaf(wq.w, pv0, a0[iq * 4 + 3]);
            a1[iq * 4 + 0] = fmaf(wq.x, pv1, a1[iq * 4 + 0]);
            a1[iq * 4 + 1] = fmaf(wq.y, pv1, a1[iq * 4 + 1]);
            a1[iq * 4 + 2] = fmaf(wq.z, pv1, a1[iq * 4 + 2]);
            a1[iq * 4 + 3] = fmaf(wq.w, pv1, a1[iq * 4 + 3]);
          }
        }
      }
    }
  }

  // epilogue (R2-proven): bias+relu + partial 1x1 convs (3 obj + 12 delta),
  // cross-wave reduce in fixed wave order (= channel order 0..255) -> deterministic
  const int co0 = __builtin_amdgcn_readfirstlane(wv << 5);
#pragma unroll
  for (int h = 0; h < 2; ++h) {
    float part[15];
#pragma unroll
    for (int f = 0; f < 15; ++f) part[f] = 0.f;
#pragma unroll
    for (int i = 0; i < 32; ++i) {
      float v = (h ? a1[i] : a0[i]) + cb[co0 + i];
      float tv = fmaxf(v, 0.f);
#pragma unroll
      for (int f = 0; f < 3; ++f)  part[f]     = fmaf(tv, ow[f * 256 + co0 + i],  part[f]);
#pragma unroll
      for (int f = 0; f < 12; ++f) part[3 + f] = fmaf(tv, dwt[f * 256 + co0 + i], part[3 + f]);
    }
    __syncthreads();
#pragma unroll
    for (int f = 0; f < 15; ++f) lds[wv * 960 + f * 64 + lane] = part[f];
    __syncthreads();
    for (int tt = tid; tt < 960; tt += 512) {
      float s = 0.f;
#pragma unroll
      for (int w2 = 0; w2 < 8; ++w2) s += lds[w2 * 960 + tt];   // fixed order: deterministic
      int f = tt >> 6, pp = tt & 63;
      int gx = px0 + (pp & 15), gy = py0 + (pp >> 4) + 4 * h;
      int cell = gy * W + gx;
      if (f < 3) {
        logits[(size_t)n * S_TOT + loff + cell * 3 + f] = s + ob[f];
      } else {
        int chn = f - 3, a = chn >> 2, c = chn & 3;
        deltas[(((size_t)n * S_TOT + loff + cell * 3 + a) << 2) + c] = s + db[chn];
      }
    }
  }
}

// ---------------- kernel 3: exact top-K + box decode per (image, level) ----------------
__global__ __launch_bounds__(1024) void topk_kernel(
    const float* __restrict__ logits, const float* __restrict__ deltas,
    float* __restrict__ selscore, float* __restrict__ selbox,
    unsigned* __restrict__ selvalid)
{
  const int tid = threadIdx.x;
  const int nl = blockIdx.x, n = nl / 5, l = nl % 5;
  const int Sl = c_S[l], loff = c_loff[l], Kl = c_K[l], Wl = c_Wl[l], strl = c_str[l];
  const float* sc = logits + (size_t)n * S_TOT + loff;

  __shared__ unsigned hist[256];
  __shared__ unsigned sh_prefix, sh_need, s_base, s_cb;
  __shared__ unsigned waveTot[16], waveOff[16];
  __shared__ unsigned long long sortbuf[1024];

  // phase 1: 4-pass radix histogram -> exact Kl-th largest key
  unsigned prefix = 0, need = (unsigned)Kl;
  for (int p = 0; p < 4; ++p) {
    for (int i = tid; i < 256; i += 1024) hist[i] = 0;
    __syncthreads();
    const int shift = 24 - p * 8;
    for (int i = tid; i < Sl; i += 1024) {
      unsigned k = key_of(sc[i]);
      if (p == 0 || (k >> (shift + 8)) == prefix)
        atomicAdd(&hist[(k >> shift) & 255u], 1u);
    }
    __syncthreads();
    if (tid == 0) {
      unsigned cum = 0;
      for (int b = 255; b >= 0; --b) {
        unsigned c = hist[b];
        if (cum + c >= need) { sh_prefix = (prefix << 8) | (unsigned)b; sh_need = need - cum; break; }
        cum += c;
      }
    }
    __syncthreads();
    prefix = sh_prefix; need = sh_need;
    __syncthreads();
  }
  const unsigned Tkey = prefix;

  // phase 2: stable compaction (strictly-greater, then equals capped) -> exactly Kl entries
  if (tid == 0) s_base = 0;
  __syncthreads();
  for (int pass = 0; pass < 2; ++pass) {
    for (int st = 0; st < Sl; st += 1024) {
      const int i = st + tid;
      bool flag = false; unsigned k = 0;
      if (i < Sl) {
        k = key_of(sc[i]);
        flag = (pass == 0) ? (k > Tkey) : (k == Tkey);
      }
      unsigned long long m = __ballot(flag);
      const int lane = tid & 63, w = tid >> 6;
      unsigned mypre = (unsigned)__popcll(m & ((1ull << lane) - 1ull));
      if (lane == 0) waveTot[w] = (unsigned)__popcll(m);
      __syncthreads();
      if (tid == 0) {
        unsigned ss = 0;
        for (int q = 0; q < 16; ++q) { waveOff[q] = ss; ss += waveTot[q]; }
        s_cb = s_base; s_base += ss;
      }
      __syncthreads();
      if (flag) {
        unsigned pos = s_cb + waveOff[w] + mypre;
        if (pos < (unsigned)Kl)
          sortbuf[pos] = (((unsigned long long)k) << 32) |
                         (unsigned long long)(0xFFFFFFFFu - (unsigned)i);
      }
      __syncthreads();
    }
  }
  if (tid >= Kl) sortbuf[tid] = (unsigned long long)(0xFFFFFFFFu - (unsigned)tid); // pads: key 0
  __syncthreads();

  // phase 3: bitonic sort of 1024 u64, descending (key desc, idx asc via ~idx)
  for (int k2 = 2; k2 <= 1024; k2 <<= 1) {
    for (int j = k2 >> 1; j > 0; j >>= 1) {
      const int i = tid, ixj = i ^ j;
      if (ixj > i) {
        unsigned long long a = sortbuf[i], b = sortbuf[ixj];
        const bool desc = (i & k2) == 0;
        if (desc ? (a < b) : (a > b)) { sortbuf[i] = b; sortbuf[ixj] = a; }
      }
      __syncthreads();
    }
  }

  // phase 4: decode boxes (anchors in f64 to bit-match np reference)
  const int r = tid;
  const int o = nl * 1024 + r;
  if (r < Kl) {
    unsigned long long v = sortbuf[r];
    unsigned k = (unsigned)(v >> 32);
    unsigned ai = 0xFFFFFFFFu - (unsigned)(v & 0xFFFFFFFFull);
    float score = key_dec(k);
    int cell = (int)(ai / 3u), a = (int)(ai % 3u);
    int xg = cell % Wl, yg = cell / Wl;
    double rr = c_rat[a], sz = c_sz[l];
    double wsd = sqrt(sz * sz / rr);
    double hw = 0.5 * wsd, hh = 0.5 * wsd * rr;
    double xs = (double)(xg * strl), ys = (double)(yg * strl);
    float a0 = (float)(xs - hw), a1 = (float)(ys - hh);
    float a2 = (float)(xs + hw), a3 = (float)(ys + hh);
    const float* dp = deltas + (((size_t)n * S_TOT + loff + ai) << 2);
    float dx = dp[0], dy = dp[1], dw_ = dp[2], dh_ = dp[3];
    float aw = a2 - a0, ah = a3 - a1;
    float cx = a0 + 0.5f * aw, cy = a1 + 0.5f * ah;
    dw_ = fminf(dw_, (float)SCLD); dh_ = fminf(dh_, (float)SCLD);
    float pcx = dx * aw + cx, pcy = dy * ah + cy;
    float pw = expf(dw_) * aw, ph = expf(dh_) * ah;
    float b0 = fminf(fmaxf(pcx - 0.5f * pw, 0.f), 1024.f);
    float b1 = fminf(fmaxf(pcy - 0.5f * ph, 0.f), 1024.f);
    float b2 = fminf(fmaxf(pcx + 0.5f * pw, 0.f), 1024.f);
    float b3 = fminf(fmaxf(pcy + 0.5f * ph, 0.f), 1024.f);
    unsigned valid = ((b2 - b0) > 0.f && (b3 - b1) > 0.f) ? 1u : 0u;
    selscore[o] = score;
    selbox[o * 4 + 0] = b0; selbox[o * 4 + 1] = b1;
    selbox[o * 4 + 2] = b2; selbox[o * 4 + 3] = b3;
    selvalid[o] = valid;
  } else {
    selscore[o] = -1e9f;
    selbox[o * 4 + 0] = 0.f; selbox[o * 4 + 1] = 0.f;
    selbox[o * 4 + 2] = 0.f; selbox[o * 4 + 3] = 0.f;
    selvalid[o] = 0u;
  }
}

// ---------------- kernel 4: NMS suppression bitmask matrix ----------------
__global__ __launch_bounds__(256) void nms_sup(
    const float* __restrict__ selbox, unsigned long long* __restrict__ sup)
{
  int gid = blockIdx.x * 256 + threadIdx.x;  // 10 * 1024 * 16
  int w = gid & 15, i = (gid >> 4) & 1023, nl = gid >> 14;
  if (nl >= 10) return;
  int l = nl % 5, Kl = c_K[l];
  unsigned long long bits = 0;
  if (i < Kl) {
    const float* bi = selbox + (size_t)(nl * 1024 + i) * 4;
    float x0 = bi[0], y0 = bi[1], x1 = bi[2], y1 = bi[3];
    float ar = (x1 - x0) * (y1 - y0);
    int jlo = w * 64; if (jlo < i + 1) jlo = i + 1;
    int jhi = w * 64 + 64; if (jhi > Kl) jhi = Kl;
    for (int j = jlo; j < jhi; ++j) {
      const float* bj = selbox + (size_t)(nl * 1024 + j) * 4;
      float u0 = fmaxf(x0, bj[0]), v0 = fmaxf(y0, bj[1]);
      float u1 = fminf(x1, bj[2]), v1 = fminf(y1, bj[3]);
      float iw = fmaxf(u1 - u0, 0.f), ih = fmaxf(v1 - v0, 0.f);
      float inter = iw * ih;
      float aj = (bj[2] - bj[0]) * (bj[3] - bj[1]);
      float iou = inter / fmaxf(ar + aj - inter, 1e-9f);
      if (iou > 0.7f) bits |= 1ull << (j - w * 64);
    }
  }
  sup[(size_t)(nl * 1024 + i) * 16 + w] = bits;
}

// ---------------- kernel 5: sequential greedy NMS reduce (1 wave / (n,l)) ----------------
__global__ __launch_bounds__(64) void nms_reduce(
    const unsigned* __restrict__ selvalid, const unsigned long long* __restrict__ sup,
    const float* __restrict__ selscore, float* __restrict__ scnms)
{
  const int nl = blockIdx.x, tid = threadIdx.x;
  const int l = nl % 5, Kl = c_K[l];
  unsigned long long keep = 0;
  if (tid < 16) {
    for (int t = 0; t < 64; ++t) {
      int r = tid * 64 + t;
      if (r < Kl && selvalid[nl * 1024 + r]) keep |= 1ull << t;
    }
  }
  const unsigned long long* srow = sup + (size_t)nl * 1024 * 16;
  unsigned long long rowA = (tid < 16) ? srow[(size_t)0 * 16 + tid] : 0;
  unsigned long long rowB = (tid < 16 && Kl > 1) ? srow[(size_t)1 * 16 + tid] : 0;
  for (int i = 0; i < Kl; i += 2) {   // Kl is even (1000 / 768)
    unsigned long long kw = __shfl(keep, i >> 6);
    unsigned long long cur = rowA;
    rowA = (tid < 16 && i + 2 < Kl) ? srow[(size_t)(i + 2) * 16 + tid] : 0;
    if (((kw >> (i & 63)) & 1ull) && tid < 16) keep &= ~cur;
    kw = __shfl(keep, (i + 1) >> 6);
    cur = rowB;
    rowB = (tid < 16 && i + 3 < Kl) ? srow[(size_t)(i + 3) * 16 + tid] : 0;
    if (((kw >> ((i + 1) & 63)) & 1ull) && tid < 16) keep &= ~cur;
  }
  for (int r = tid; r < 1024; r += 64) {
    unsigned long long wv = __shfl(keep, r >> 6);
    bool kp = (r < Kl) && ((wv >> (r & 63)) & 1ull);
    scnms[nl * 1024 + r] = kp ? selscore[nl * 1024 + r] : -1e9f;
  }
}

// ---------------- kernel 6: final per-image top-1000 of 4768 + output ----------------
DEVI float cand_score(const float* scnms, int n, int g) {
  int l = g / 1000;               // g < 4768 -> l in [0,4]
  int r = g - l * 1000;
  return scnms[((n * 5 + l) << 10) + r];
}

__global__ __launch_bounds__(1024) void final_topk(
    const float* __restrict__ scnms, const float* __restrict__ selbox,
    float* __restrict__ out)
{
  const int tid = threadIdx.x;
  const int n = blockIdx.x;
  const int S = 4768;

  __shared__ unsigned hist[256];
  __shared__ unsigned sh_prefix, sh_need, s_base, s_cb;
  __shared__ unsigned waveTot[16], waveOff[16];
  __shared__ unsigned long long sortbuf[1024];

  unsigned prefix = 0, need = 1000;
  for (int p = 0; p < 4; ++p) {
    for (int i = tid; i < 256; i += 1024) hist[i] = 0;
    __syncthreads();
    const int shift = 24 - p * 8;
    for (int i = tid; i < S; i += 1024) {
      unsigned k = key_of(cand_score(scnms, n, i));
      if (p == 0 || (k >> (shift + 8)) == prefix)
        atomicAdd(&hist[(k >> shift) & 255u], 1u);
    }
    __syncthreads();
    if (tid == 0) {
      unsigned cum = 0;
      for (int b = 255; b >= 0; --b) {
        unsigned c = hist[b];
        if (cum + c >= need) { sh_prefix = (prefix << 8) | (unsigned)b; sh_need = need - cum; break; }
        cum += c;
      }
    }
    __syncthreads();
    prefix = sh_prefix; need = sh_need;
    __syncthreads();
  }
  const unsigned Tkey = prefix;

  if (tid == 0) s_base = 0;
  __syncthreads();
  for (int pass = 0; pass < 2; ++pass) {
    for (int st = 0; st < S; st += 1024) {
      const int i = st + tid;
      bool flag = false; unsigned k = 0;
      if (i < S) {
        k = key_of(cand_score(scnms, n, i));
        flag = (pass == 0) ? (k > Tkey) : (k == Tkey);
      }
      unsigned long long m = __ballot(flag);
      const int lane = tid & 63, w = tid >> 6;
      unsigned mypre = (unsigned)__popcll(m & ((1ull << lane) - 1ull));
      if (lane == 0) waveTot[w] = (unsigned)__popcll(m);
      __syncthreads();
      if (tid == 0) {
        unsigned ss = 0;
        for (int q = 0; q < 16; ++q) { waveOff[q] = ss; ss += waveTot[q]; }
        s_cb = s_base; s_base += ss;
      }
      __syncthreads();
      if (flag) {
        unsigned pos = s_cb + waveOff[w] + mypre;
        if (pos < 1000u)
          sortbuf[pos] = (((unsigned long long)k) << 32) |
                         (unsigned long long)(0xFFFFFFFFu - (unsigned)i);
      }
      __syncthreads();
    }
  }
  if (tid >= 1000) sortbuf[tid] = (unsigned long long)(0xFFFFFFFFu - (unsigned)tid);
  __syncthreads();

  for (int k2 = 2; k2 <= 1024; k2 <<= 1) {
    for (int j = k2 >> 1; j > 0; j >>= 1) {
      const int i = tid, ixj = i ^ j;
      if (ixj > i) {
        unsigned long long a = sortbuf[i], b = sortbuf[ixj];
        const bool desc = (i & k2) == 0;
        if (desc ? (a < b) : (a > b)) { sortbuf[i] = b; sortbuf[ixj] = a; }
      }
      __syncthreads();
    }
  }

  if (tid < 1000) {
    unsigned long long v = sortbuf[tid];
    unsigned k = (unsigned)(v >> 32);
    int g = (int)(0xFFFFFFFFu - (unsigned)(v & 0xFFFFFFFFull));
    int l = g / 1000, r = g - l * 1000;
    const float* b = selbox + ((size_t)((n * 5 + l) * 1024 + r)) * 4;
    size_t ob_ = ((size_t)n * 1000 + tid) * 4;
    out[ob_ + 0] = b[0]; out[ob_ + 1] = b[1];
    out[ob_ + 2] = b[2]; out[ob_ + 3] = b[3];
    out[8000 + n * 1000 + tid] = key_dec(k);
  }
}

// ---------------- host launcher ----------------
extern "C" void kernel_launch(void* const* d_in, const int* in_sizes, int n_in,
                              void* d_out, int out_size, void* d_ws, size_t ws_size,
                              hipStream_t stream)
{
  const float* feats[5];
  for (int i = 0; i < 5; ++i) feats[i] = (const float*)d_in[i];
  const float* conv_w  = (const float*)d_in[5];
  const float* conv_b  = (const float*)d_in[6];
  const float* obj_w   = (const float*)d_in[7];
  const float* obj_b   = (const float*)d_in[8];
  const float* delta_w = (const float*)d_in[9];
  const float* delta_b = (const float*)d_in[10];

  char* wsp = (char*)d_ws;
  float* wT3      = (float*)wsp;  wsp += (size_t)2304 * 256 * 4;     // 2.36 MB
  float* logits   = (float*)wsp;  wsp += (size_t)NIMG * S_TOT * 4;   // 2.10 MB
  float* deltas   = (float*)wsp;  wsp += (size_t)NIMG * S_TOT * 16;  // 8.38 MB
  float* selscore = (float*)wsp;  wsp += (size_t)10 * 1024 * 4;
  float* selbox   = (float*)wsp;  wsp += (size_t)10 * 1024 * 16;
  unsigned* selvalid = (unsigned*)wsp; wsp += (size_t)10 * 1024 * 4;
  float* scnms    = (float*)wsp;  wsp += (size_t)10 * 1024 * 4;
  unsigned long long* sup = (unsigned long long*)wsp;
  wsp += (size_t)10 * 1024 * 16 * 8;                                 // 1.31 MB

  transpose_w<<<dim3(2304), dim3(256), 0, stream>>>(conv_w, wT3);

  conv_fused<<<dim3(682, NIMG), dim3(512), 0, stream>>>(
      feats[0], feats[1], feats[2], feats[3], feats[4],
      wT3, conv_b, obj_w, obj_b, delta_w, delta_b, logits, deltas);

  topk_kernel<<<dim3(10), dim3(1024), 0, stream>>>(logits, deltas,
                                                   selscore, selbox, selvalid);
  nms_sup<<<dim3(640), dim3(256), 0, stream>>>(selbox, sup);
  nms_reduce<<<dim3(10), dim3(64), 0, stream>>>(selvalid, sup, selscore, scnms);
  final_topk<<<dim3(NIMG), dim3(1024), 0, stream>>>(scnms, selbox, (float*)d_out);
}

// Round 7
// 3370.160 us; speedup vs baseline: 1.4520x; 1.0963x over previous
//
#include <hip/hip_runtime.h>
#include <stdint.h>

#define DEVI __device__ __forceinline__

#define S_TOT 261888
#define NIMG  2
#define SCLD  4.135166556742356   // log(1000/16)

// ---------------- constant tables (all compile-time) ----------------
__constant__ int    c_S[5]    = {196608, 49152, 12288, 3072, 768};
__constant__ int    c_loff[5] = {0, 196608, 245760, 258048, 261120};
__constant__ int    c_K[5]    = {1000, 1000, 1000, 1000, 768};
__constant__ int    c_Wl[5]   = {256, 128, 64, 32, 16};
__constant__ int    c_str[5]  = {4, 8, 16, 32, 64};
__constant__ double c_sz[5]   = {32.0, 64.0, 128.0, 256.0, 512.0};
__constant__ double c_rat[3]  = {0.5, 1.0, 2.0};
// merged conv block decode: tiles are 16x16 px; per-level block counts {256,64,16,4,1}
__constant__ int    c_boff[6] = {0, 256, 320, 336, 340, 341};
__constant__ int    c_Hl[5]   = {256, 128, 64, 32, 16};

// order-preserving float<->uint key (ascending key == ascending float)
DEVI unsigned key_of(float f) {
  unsigned u = __float_as_uint(f);
  return (u & 0x80000000u) ? ~u : (u | 0x80000000u);
}
DEVI float key_dec(unsigned k) {
  unsigned u = (k & 0x80000000u) ? (k & 0x7fffffffu) : ~k;
  return __uint_as_float(u);
}

// ---------------- kernel 1: weight relayout for LDS-broadcast consumption ----------------
// wT4[chunk*18432 + cc*2304 + g*144 + j*16 + i] = w[co][ci*9+j]
// with co = g*16+i (g = wave 0..15, i = cout-in-wave), ci = chunk*8+cc.
// Each chunk is a flat 18432-dword run -> coalesced float4 staging into LDS;
// per (cc,g) a contiguous 144-dword run -> uniform-address ds_read_b128 broadcast.
__global__ void transpose_w(const float* __restrict__ w, float* __restrict__ wT4) {
  int k  = blockIdx.x;   // 0..2303  (ci*9 + j)
  int co = threadIdx.x;  // 0..255
  int ci = k / 9, j = k - ci * 9;
  int chunk = ci >> 3, cc = ci & 7;
  int g = co >> 4, i = co & 15;
  wT4[(size_t)chunk * 18432 + cc * 2304 + g * 144 + j * 16 + i] = w[co * 2304 + k];
}

// ---------------- kernel 2: fused conv3x3+bias+relu then 1x1 obj/delta, ALL levels in one grid ----
// block = 1024 thr (16 waves). tile = 16x16 px, lane owns 4 px (rows p,p+4,p+8,p+12);
// wave w owns couts [16w,16w+16) -> all 256 couts in ONE pass (weights amortized 4 px/read).
// Weights per 8-ci chunk staged to LDS, read via wave-uniform ds_read_b128 (broadcast).
// FMA order per accumulator: ci ascending, tap (ky,kx) ascending — bit-identical to ref.
// 1x1 sum: 16 ascending groups of 16 channels == R2's proven exact order.
__global__ __launch_bounds__(1024, 4) void conv_fused(
    const float* __restrict__ x0, const float* __restrict__ x1,
    const float* __restrict__ x2, const float* __restrict__ x3,
    const float* __restrict__ x4,
    const float* __restrict__ wT4,
    const float* __restrict__ cb, const float* __restrict__ ow,
    const float* __restrict__ ob, const float* __restrict__ dwt,
    const float* __restrict__ db, float* __restrict__ logits,
    float* __restrict__ deltas)
{
  __shared__ float lds[21024];  // 84 KB: patch [0,2592) + weights [2592,21024); reduce aliases [0,15360)
  float* const wlds = lds + 2592;
  const int tid = threadIdx.x;
  const int n = blockIdx.y;
  const int b = blockIdx.x;
  int l = 0;
#pragma unroll
  for (int q = 1; q < 5; ++q) if (b >= c_boff[q]) l = q;
  const int t = b - c_boff[l];
  const int H = c_Hl[l], W = H;
  const int tilesx = 16 >> l;
  const int tx = t & (tilesx - 1), ty = t >> (4 - l);
  const int px0 = tx << 4, py0 = ty << 4;
  const int loff = c_loff[l];
  const float* xin = (l == 0) ? x0 : (l == 1) ? x1 : (l == 2) ? x2 : (l == 3) ? x3 : x4;
  xin += (size_t)n * 256 * H * W;

  const int lane = tid & 63, wv = tid >> 6;      // wv 0..15
  const int px = lane & 15, p = lane >> 4;       // p 0..3; lane owns rows p,p+4,p+8,p+12

  float acc[64];                                 // [k 0..3][cout-in-wave 0..15]
#pragma unroll
  for (int i = 0; i < 64; ++i) acc[i] = 0.f;

  for (int ch = 0; ch < 32; ++ch) {              // 32 chunks of 8 input channels
    const int ci0 = ch << 3;
    __syncthreads();
    // stage input patch 8ci x 18 x 18 (zero-padded halo): 2592 floats
    for (int tt = tid; tt < 2592; tt += 1024) {
      int ci = tt / 324, rem = tt - ci * 324;
      int ry = rem / 18, rx = rem - ry * 18;
      int gy = py0 + ry - 1, gx = px0 + rx - 1;
      float v = 0.f;
      if (gy >= 0 && gy < H && gx >= 0 && gx < W)
        v = xin[((size_t)(ci0 + ci) * H + gy) * W + gx];
      lds[tt] = v;
    }
    // stage this chunk's weights: flat 18432 dwords, coalesced float4
    {
      const float4* wg = (const float4*)(wT4 + (size_t)ch * 18432);
      float4* wl = (float4*)wlds;
      for (int tt = tid; tt < 4608; tt += 1024) wl[tt] = wg[tt];
    }
    __syncthreads();
#pragma unroll 1
    for (int cc = 0; cc < 8; ++cc) {
      const float* wr = wlds + cc * 2304 + wv * 144;   // wave-uniform base -> broadcast reads
      const int pb = cc * 324 + p * 18 + px;
#pragma unroll 1
      for (int ky = 0; ky < 3; ++ky) {
        const int rb = pb + ky * 18;
        // 12 patch values: rows (p+4k+ky) k=0..3, cols px..px+2
        float q0[3], q1[3], q2[3], q3[3];
#pragma unroll
        for (int c = 0; c < 3; ++c) {
          q0[c] = lds[rb + c];
          q1[c] = lds[rb + 72 + c];
          q2[c] = lds[rb + 144 + c];
          q3[c] = lds[rb + 216 + c];
        }
        const float* wk = wr + ky * 48;
#pragma unroll
        for (int kx = 0; kx < 3; ++kx) {
          const float* wt = wk + kx * 16;
          const float4 wa = *(const float4*)(wt + 0);
          const float4 wb = *(const float4*)(wt + 4);
          const float4 wc = *(const float4*)(wt + 8);
          const float4 wd = *(const float4*)(wt + 12);
          const float v0 = q0[kx], v1 = q1[kx], v2 = q2[kx], v3 = q3[kx];
          acc[ 0] = fmaf(wa.x, v0, acc[ 0]); acc[ 1] = fmaf(wa.y, v0, acc[ 1]);
          acc[ 2] = fmaf(wa.z, v0, acc[ 2]); acc[ 3] = fmaf(wa.w, v0, acc[ 3]);
          acc[ 4] = fmaf(wb.x, v0, acc[ 4]); acc[ 5] = fmaf(wb.y, v0, acc[ 5]);
          acc[ 6] = fmaf(wb.z, v0, acc[ 6]); acc[ 7] = fmaf(wb.w, v0, acc[ 7]);
          acc[ 8] = fmaf(wc.x, v0, acc[ 8]); acc[ 9] = fmaf(wc.y, v0, acc[ 9]);
          acc[10] = fmaf(wc.z, v0, acc[10]); acc[11] = fmaf(wc.w, v0, acc[11]);
          acc[12] = fmaf(wd.x, v0, acc[12]); acc[13] = fmaf(wd.y, v0, acc[13]);
          acc[14] = fmaf(wd.z, v0, acc[14]); acc[15] = fmaf(wd.w, v0, acc[15]);
          acc[16] = fmaf(wa.x, v1, acc[16]); acc[17] = fmaf(wa.y, v1, acc[17]);
          acc[18] = fmaf(wa.z, v1, acc[18]); acc[19] = fmaf(wa.w, v1, acc[19]);
          acc[20] = fmaf(wb.x, v1, acc[20]); acc[21] = fmaf(wb.y, v1, acc[21]);
          acc[22] = fmaf(wb.z, v1, acc[22]); acc[23] = fmaf(wb.w, v1, acc[23]);
          acc[24] = fmaf(wc.x, v1, acc[24]); acc[25] = fmaf(wc.y, v1, acc[25]);
          acc[26] = fmaf(wc.z, v1, acc[26]); acc[27] = fmaf(wc.w, v1, acc[27]);
          acc[28] = fmaf(wd.x, v1, acc[28]); acc[29] = fmaf(wd.y, v1, acc[29]);
          acc[30] = fmaf(wd.z, v1, acc[30]); acc[31] = fmaf(wd.w, v1, acc[31]);
          acc[32] = fmaf(wa.x, v2, acc[32]); acc[33] = fmaf(wa.y, v2, acc[33]);
          acc[34] = fmaf(wa.z, v2, acc[34]); acc[35] = fmaf(wa.w, v2, acc[35]);
          acc[36] = fmaf(wb.x, v2, acc[36]); acc[37] = fmaf(wb.y, v2, acc[37]);
          acc[38] = fmaf(wb.z, v2, acc[38]); acc[39] = fmaf(wb.w, v2, acc[39]);
          acc[40] = fmaf(wc.x, v2, acc[40]); acc[41] = fmaf(wc.y, v2, acc[41]);
          acc[42] = fmaf(wc.z, v2, acc[42]); acc[43] = fmaf(wc.w, v2, acc[43]);
          acc[44] = fmaf(wd.x, v2, acc[44]); acc[45] = fmaf(wd.y, v2, acc[45]);
          acc[46] = fmaf(wd.z, v2, acc[46]); acc[47] = fmaf(wd.w, v2, acc[47]);
          acc[48] = fmaf(wa.x, v3, acc[48]); acc[49] = fmaf(wa.y, v3, acc[49]);
          acc[50] = fmaf(wa.z, v3, acc[50]); acc[51] = fmaf(wa.w, v3, acc[51]);
          acc[52] = fmaf(wb.x, v3, acc[52]); acc[53] = fmaf(wb.y, v3, acc[53]);
          acc[54] = fmaf(wb.z, v3, acc[54]); acc[55] = fmaf(wb.w, v3, acc[55]);
          acc[56] = fmaf(wc.x, v3, acc[56]); acc[57] = fmaf(wc.y, v3, acc[57]);
          acc[58] = fmaf(wc.z, v3, acc[58]); acc[59] = fmaf(wc.w, v3, acc[59]);
          acc[60] = fmaf(wd.x, v3, acc[60]); acc[61] = fmaf(wd.y, v3, acc[61]);
          acc[62] = fmaf(wd.z, v3, acc[62]); acc[63] = fmaf(wd.w, v3, acc[63]);
        }
      }
    }
  }

  // epilogue: bias+relu + partial 1x1 convs (3 obj + 12 delta) over this wave's 16 ch,
  // cross-wave reduce in fixed wave order (= channel order 0..255) -> deterministic
  const int co0 = __builtin_amdgcn_readfirstlane(wv << 4);
#pragma unroll
  for (int h = 0; h < 4; ++h) {
    float part[15];
#pragma unroll
    for (int f = 0; f < 15; ++f) part[f] = 0.f;
#pragma unroll
    for (int i = 0; i < 16; ++i) {
      float tv = fmaxf(acc[h * 16 + i] + cb[co0 + i], 0.f);
#pragma unroll
      for (int f = 0; f < 3; ++f)  part[f]     = fmaf(tv, ow[f * 256 + co0 + i],  part[f]);
#pragma unroll
      for (int f = 0; f < 12; ++f) part[3 + f] = fmaf(tv, dwt[f * 256 + co0 + i], part[3 + f]);
    }
    __syncthreads();
#pragma unroll
    for (int f = 0; f < 15; ++f) lds[wv * 960 + f * 64 + lane] = part[f];
    __syncthreads();
    for (int tt = tid; tt < 960; tt += 1024) {
      float s = 0.f;
#pragma unroll
      for (int w2 = 0; w2 < 16; ++w2) s += lds[w2 * 960 + tt];  // fixed order: deterministic
      int f = tt >> 6, pp = tt & 63;
      int gx = px0 + (pp & 15), gy = py0 + (pp >> 4) + 4 * h;
      int cell = gy * W + gx;
      if (f < 3) {
        logits[(size_t)n * S_TOT + loff + cell * 3 + f] = s + ob[f];
      } else {
        int chn = f - 3, a = chn >> 2, c = chn & 3;
        deltas[(((size_t)n * S_TOT + loff + cell * 3 + a) << 2) + c] = s + db[chn];
      }
    }
  }
}

// ---------------- kernel 3: exact top-K + box decode per (image, level) ----------------
__global__ __launch_bounds__(1024) void topk_kernel(
    const float* __restrict__ logits, const float* __restrict__ deltas,
    float* __restrict__ selscore, float* __restrict__ selbox,
    unsigned* __restrict__ selvalid)
{
  const int tid = threadIdx.x;
  const int nl = blockIdx.x, n = nl / 5, l = nl % 5;
  const int Sl = c_S[l], loff = c_loff[l], Kl = c_K[l], Wl = c_Wl[l], strl = c_str[l];
  const float* sc = logits + (size_t)n * S_TOT + loff;

  __shared__ unsigned hist[256];
  __shared__ unsigned sh_prefix, sh_need, s_base, s_cb;
  __shared__ unsigned waveTot[16], waveOff[16];
  __shared__ unsigned long long sortbuf[1024];

  // phase 1: 4-pass radix histogram -> exact Kl-th largest key
  unsigned prefix = 0, need = (unsigned)Kl;
  for (int p = 0; p < 4; ++p) {
    for (int i = tid; i < 256; i += 1024) hist[i] = 0;
    __syncthreads();
    const int shift = 24 - p * 8;
    for (int i = tid; i < Sl; i += 1024) {
      unsigned k = key_of(sc[i]);
      if (p == 0 || (k >> (shift + 8)) == prefix)
        atomicAdd(&hist[(k >> shift) & 255u], 1u);
    }
    __syncthreads();
    if (tid == 0) {
      unsigned cum = 0;
      for (int b = 255; b >= 0; --b) {
        unsigned c = hist[b];
        if (cum + c >= need) { sh_prefix = (prefix << 8) | (unsigned)b; sh_need = need - cum; break; }
        cum += c;
      }
    }
    __syncthreads();
    prefix = sh_prefix; need = sh_need;
    __syncthreads();
  }
  const unsigned Tkey = prefix;

  // phase 2: stable compaction (strictly-greater, then equals capped) -> exactly Kl entries
  if (tid == 0) s_base = 0;
  __syncthreads();
  for (int pass = 0; pass < 2; ++pass) {
    for (int st = 0; st < Sl; st += 1024) {
      const int i = st + tid;
      bool flag = false; unsigned k = 0;
      if (i < Sl) {
        k = key_of(sc[i]);
        flag = (pass == 0) ? (k > Tkey) : (k == Tkey);
      }
      unsigned long long m = __ballot(flag);
      const int lane = tid & 63, w = tid >> 6;
      unsigned mypre = (unsigned)__popcll(m & ((1ull << lane) - 1ull));
      if (lane == 0) waveTot[w] = (unsigned)__popcll(m);
      __syncthreads();
      if (tid == 0) {
        unsigned ss = 0;
        for (int q = 0; q < 16; ++q) { waveOff[q] = ss; ss += waveTot[q]; }
        s_cb = s_base; s_base += ss;
      }
      __syncthreads();
      if (flag) {
        unsigned pos = s_cb + waveOff[w] + mypre;
        if (pos < (unsigned)Kl)
          sortbuf[pos] = (((unsigned long long)k) << 32) |
                         (unsigned long long)(0xFFFFFFFFu - (unsigned)i);
      }
      __syncthreads();
    }
  }
  if (tid >= Kl) sortbuf[tid] = (unsigned long long)(0xFFFFFFFFu - (unsigned)tid); // pads: key 0
  __syncthreads();

  // phase 3: bitonic sort of 1024 u64, descending (key desc, idx asc via ~idx)
  for (int k2 = 2; k2 <= 1024; k2 <<= 1) {
    for (int j = k2 >> 1; j > 0; j >>= 1) {
      const int i = tid, ixj = i ^ j;
      if (ixj > i) {
        unsigned long long a = sortbuf[i], b = sortbuf[ixj];
        const bool desc = (i & k2) == 0;
        if (desc ? (a < b) : (a > b)) { sortbuf[i] = b; sortbuf[ixj] = a; }
      }
      __syncthreads();
    }
  }

  // phase 4: decode boxes (anchors in f64 to bit-match np reference)
  const int r = tid;
  const int o = nl * 1024 + r;
  if (r < Kl) {
    unsigned long long v = sortbuf[r];
    unsigned k = (unsigned)(v >> 32);
    unsigned ai = 0xFFFFFFFFu - (unsigned)(v & 0xFFFFFFFFull);
    float score = key_dec(k);
    int cell = (int)(ai / 3u), a = (int)(ai % 3u);
    int xg = cell % Wl, yg = cell / Wl;
    double rr = c_rat[a], sz = c_sz[l];
    double wsd = sqrt(sz * sz / rr);
    double hw = 0.5 * wsd, hh = 0.5 * wsd * rr;
    double xs = (double)(xg * strl), ys = (double)(yg * strl);
    float a0 = (float)(xs - hw), a1 = (float)(ys - hh);
    float a2 = (float)(xs + hw), a3 = (float)(ys + hh);
    const float* dp = deltas + (((size_t)n * S_TOT + loff + ai) << 2);
    float dx = dp[0], dy = dp[1], dw_ = dp[2], dh_ = dp[3];
    float aw = a2 - a0, ah = a3 - a1;
    float cx = a0 + 0.5f * aw, cy = a1 + 0.5f * ah;
    dw_ = fminf(dw_, (float)SCLD); dh_ = fminf(dh_, (float)SCLD);
    float pcx = dx * aw + cx, pcy = dy * ah + cy;
    float pw = expf(dw_) * aw, ph = expf(dh_) * ah;
    float b0 = fminf(fmaxf(pcx - 0.5f * pw, 0.f), 1024.f);
    float b1 = fminf(fmaxf(pcy - 0.5f * ph, 0.f), 1024.f);
    float b2 = fminf(fmaxf(pcx + 0.5f * pw, 0.f), 1024.f);
    float b3 = fminf(fmaxf(pcy + 0.5f * ph, 0.f), 1024.f);
    unsigned valid = ((b2 - b0) > 0.f && (b3 - b1) > 0.f) ? 1u : 0u;
    selscore[o] = score;
    selbox[o * 4 + 0] = b0; selbox[o * 4 + 1] = b1;
    selbox[o * 4 + 2] = b2; selbox[o * 4 + 3] = b3;
    selvalid[o] = valid;
  } else {
    selscore[o] = -1e9f;
    selbox[o * 4 + 0] = 0.f; selbox[o * 4 + 1] = 0.f;
    selbox[o * 4 + 2] = 0.f; selbox[o * 4 + 3] = 0.f;
    selvalid[o] = 0u;
  }
}

// ---------------- kernel 4: NMS suppression bitmask matrix ----------------
__global__ __launch_bounds__(256) void nms_sup(
    const float* __restrict__ selbox, unsigned long long* __restrict__ sup)
{
  int gid = blockIdx.x * 256 + threadIdx.x;  // 10 * 1024 * 16
  int w = gid & 15, i = (gid >> 4) & 1023, nl = gid >> 14;
  if (nl >= 10) return;
  int l = nl % 5, Kl = c_K[l];
  unsigned long long bits = 0;
  if (i < Kl) {
    const float* bi = selbox + (size_t)(nl * 1024 + i) * 4;
    float x0 = bi[0], y0 = bi[1], x1 = bi[2], y1 = bi[3];
    float ar = (x1 - x0) * (y1 - y0);
    int jlo = w * 64; if (jlo < i + 1) jlo = i + 1;
    int jhi = w * 64 + 64; if (jhi > Kl) jhi = Kl;
    for (int j = jlo; j < jhi; ++j) {
      const float* bj = selbox + (size_t)(nl * 1024 + j) * 4;
      float u0 = fmaxf(x0, bj[0]), v0 = fmaxf(y0, bj[1]);
      float u1 = fminf(x1, bj[2]), v1 = fminf(y1, bj[3]);
      float iw = fmaxf(u1 - u0, 0.f), ih = fmaxf(v1 - v0, 0.f);
      float inter = iw * ih;
      float aj = (bj[2] - bj[0]) * (bj[3] - bj[1]);
      float iou = inter / fmaxf(ar + aj - inter, 1e-9f);
      if (iou > 0.7f) bits |= 1ull << (j - w * 64);
    }
  }
  sup[(size_t)(nl * 1024 + i) * 16 + w] = bits;
}

// ---------------- kernel 5: sequential greedy NMS reduce (1 wave / (n,l)) ----------------
__global__ __launch_bounds__(64) void nms_reduce(
    const unsigned* __restrict__ selvalid, const unsigned long long* __restrict__ sup,
    const float* __restrict__ selscore, float* __restrict__ scnms)
{
  const int nl = blockIdx.x, tid = threadIdx.x;
  const int l = nl % 5, Kl = c_K[l];
  unsigned long long keep = 0;
  if (tid < 16) {
    for (int t = 0; t < 64; ++t) {
      int r = tid * 64 + t;
      if (r < Kl && selvalid[nl * 1024 + r]) keep |= 1ull << t;
    }
  }
  const unsigned long long* srow = sup + (size_t)nl * 1024 * 16;
  unsigned long long rowA = (tid < 16) ? srow[(size_t)0 * 16 + tid] : 0;
  unsigned long long rowB = (tid < 16 && Kl > 1) ? srow[(size_t)1 * 16 + tid] : 0;
  for (int i = 0; i < Kl; i += 2) {   // Kl is even (1000 / 768)
    unsigned long long kw = __shfl(keep, i >> 6);
    unsigned long long cur = rowA;
    rowA = (tid < 16 && i + 2 < Kl) ? srow[(size_t)(i + 2) * 16 + tid] : 0;
    if (((kw >> (i & 63)) & 1ull) && tid < 16) keep &= ~cur;
    kw = __shfl(keep, (i + 1) >> 6);
    cur = rowB;
    rowB = (tid < 16 && i + 3 < Kl) ? srow[(size_t)(i + 3) * 16 + tid] : 0;
    if (((kw >> ((i + 1) & 63)) & 1ull) && tid < 16) keep &= ~cur;
  }
  for (int r = tid; r < 1024; r += 64) {
    unsigned long long wv = __shfl(keep, r >> 6);
    bool kp = (r < Kl) && ((wv >> (r & 63)) & 1ull);
    scnms[nl * 1024 + r] = kp ? selscore[nl * 1024 + r] : -1e9f;
  }
}

// ---------------- kernel 6: final per-image top-1000 of 4768 + output ----------------
DEVI float cand_score(const float* scnms, int n, int g) {
  int l = g / 1000;               // g < 4768 -> l in [0,4]
  int r = g - l * 1000;
  return scnms[((n * 5 + l) << 10) + r];
}

__global__ __launch_bounds__(1024) void final_topk(
    const float* __restrict__ scnms, const float* __restrict__ selbox,
    float* __restrict__ out)
{
  const int tid = threadIdx.x;
  const int n = blockIdx.x;
  const int S = 4768;

  __shared__ unsigned hist[256];
  __shared__ unsigned sh_prefix, sh_need, s_base, s_cb;
  __shared__ unsigned waveTot[16], waveOff[16];
  __shared__ unsigned long long sortbuf[1024];

  unsigned prefix = 0, need = 1000;
  for (int p = 0; p < 4; ++p) {
    for (int i = tid; i < 256; i += 1024) hist[i] = 0;
    __syncthreads();
    const int shift = 24 - p * 8;
    for (int i = tid; i < S; i += 1024) {
      unsigned k = key_of(cand_score(scnms, n, i));
      if (p == 0 || (k >> (shift + 8)) == prefix)
        atomicAdd(&hist[(k >> shift) & 255u], 1u);
    }
    __syncthreads();
    if (tid == 0) {
      unsigned cum = 0;
      for (int b = 255; b >= 0; --b) {
        unsigned c = hist[b];
        if (cum + c >= need) { sh_prefix = (prefix << 8) | (unsigned)b; sh_need = need - cum; break; }
        cum += c;
      }
    }
    __syncthreads();
    prefix = sh_prefix; need = sh_need;
    __syncthreads();
  }
  const unsigned Tkey = prefix;

  if (tid == 0) s_base = 0;
  __syncthreads();
  for (int pass = 0; pass < 2; ++pass) {
    for (int st = 0; st < S; st += 1024) {
      const int i = st + tid;
      bool flag = false; unsigned k = 0;
      if (i < S) {
        k = key_of(cand_score(scnms, n, i));
        flag = (pass == 0) ? (k > Tkey) : (k == Tkey);
      }
      unsigned long long m = __ballot(flag);
      const int lane = tid & 63, w = tid >> 6;
      unsigned mypre = (unsigned)__popcll(m & ((1ull << lane) - 1ull));
      if (lane == 0) waveTot[w] = (unsigned)__popcll(m);
      __syncthreads();
      if (tid == 0) {
        unsigned ss = 0;
        for (int q = 0; q < 16; ++q) { waveOff[q] = ss; ss += waveTot[q]; }
        s_cb = s_base; s_base += ss;
      }
      __syncthreads();
      if (flag) {
        unsigned pos = s_cb + waveOff[w] + mypre;
        if (pos < 1000u)
          sortbuf[pos] = (((unsigned long long)k) << 32) |
                         (unsigned long long)(0xFFFFFFFFu - (unsigned)i);
      }
      __syncthreads();
    }
  }
  if (tid >= 1000) sortbuf[tid] = (unsigned long long)(0xFFFFFFFFu - (unsigned)tid);
  __syncthreads();

  for (int k2 = 2; k2 <= 1024; k2 <<= 1) {
    for (int j = k2 >> 1; j > 0; j >>= 1) {
      const int i = tid, ixj = i ^ j;
      if (ixj > i) {
        unsigned long long a = sortbuf[i], b = sortbuf[ixj];
        const bool desc = (i & k2) == 0;
        if (desc ? (a < b) : (a > b)) { sortbuf[i] = b; sortbuf[ixj] = a; }
      }
      __syncthreads();
    }
  }

  if (tid < 1000) {
    unsigned long long v = sortbuf[tid];
    unsigned k = (unsigned)(v >> 32);
    int g = (int)(0xFFFFFFFFu - (unsigned)(v & 0xFFFFFFFFull));
    int l = g / 1000, r = g - l * 1000;
    const float* b = selbox + ((size_t)((n * 5 + l) * 1024 + r)) * 4;
    size_t ob_ = ((size_t)n * 1000 + tid) * 4;
    out[ob_ + 0] = b[0]; out[ob_ + 1] = b[1];
    out[ob_ + 2] = b[2]; out[ob_ + 3] = b[3];
    out[8000 + n * 1000 + tid] = key_dec(k);
  }
}

// ---------------- host launcher ----------------
extern "C" void kernel_launch(void* const* d_in, const int* in_sizes, int n_in,
                              void* d_out, int out_size, void* d_ws, size_t ws_size,
                              hipStream_t stream)
{
  const float* feats[5];
  for (int i = 0; i < 5; ++i) feats[i] = (const float*)d_in[i];
  const float* conv_w  = (const float*)d_in[5];
  const float* conv_b  = (const float*)d_in[6];
  const float* obj_w   = (const float*)d_in[7];
  const float* obj_b   = (const float*)d_in[8];
  const float* delta_w = (const float*)d_in[9];
  const float* delta_b = (const float*)d_in[10];

  char* wsp = (char*)d_ws;
  float* wT4      = (float*)wsp;  wsp += (size_t)2304 * 256 * 4;     // 2.36 MB
  float* logits   = (float*)wsp;  wsp += (size_t)NIMG * S_TOT * 4;   // 2.10 MB
  float* deltas   = (float*)wsp;  wsp += (size_t)NIMG * S_TOT * 16;  // 8.38 MB
  float* selscore = (float*)wsp;  wsp += (size_t)10 * 1024 * 4;
  float* selbox   = (float*)wsp;  wsp += (size_t)10 * 1024 * 16;
  unsigned* selvalid = (unsigned*)wsp; wsp += (size_t)10 * 1024 * 4;
  float* scnms    = (float*)wsp;  wsp += (size_t)10 * 1024 * 4;
  unsigned long long* sup = (unsigned long long*)wsp;
  wsp += (size_t)10 * 1024 * 16 * 8;                                 // 1.31 MB

  transpose_w<<<dim3(2304), dim3(256), 0, stream>>>(conv_w, wT4);

  conv_fused<<<dim3(341, NIMG), dim3(1024), 0, stream>>>(
      feats[0], feats[1], feats[2], feats[3], feats[4],
      wT4, conv_b, obj_w, obj_b, delta_w, delta_b, logits, deltas);

  topk_kernel<<<dim3(10), dim3(1024), 0, stream>>>(logits, deltas,
                                                   selscore, selbox, selvalid);
  nms_sup<<<dim3(640), dim3(256), 0, stream>>>(selbox, sup);
  nms_reduce<<<dim3(10), dim3(64), 0, stream>>>(selvalid, sup, selscore, scnms);
  final_topk<<<dim3(NIMG), dim3(1024), 0, stream>>>(scnms, selbox, (float*)d_out);
}

// Round 8
// 3165.816 us; speedup vs baseline: 1.5457x; 1.0645x over previous
//
#include <hip/hip_runtime.h>
#include <stdint.h>

#define DEVI __device__ __forceinline__

#define S_TOT 261888
#define NIMG  2
#define SCLD  4.135166556742356   // log(1000/16)

// ---------------- constant tables (all compile-time) ----------------
__constant__ int    c_S[5]    = {196608, 49152, 12288, 3072, 768};
__constant__ int    c_loff[5] = {0, 196608, 245760, 258048, 261120};
__constant__ int    c_K[5]    = {1000, 1000, 1000, 1000, 768};
__constant__ int    c_Wl[5]   = {256, 128, 64, 32, 16};
__constant__ int    c_str[5]  = {4, 8, 16, 32, 64};
__constant__ double c_sz[5]   = {32.0, 64.0, 128.0, 256.0, 512.0};
__constant__ double c_rat[3]  = {0.5, 1.0, 2.0};
// merged conv block decode: tiles are 16x16 px; per-level block counts {256,64,16,4,1}
__constant__ int    c_boff[6] = {0, 256, 320, 336, 340, 341};
__constant__ int    c_Hl[5]   = {256, 128, 64, 32, 16};

// order-preserving float<->uint key (ascending key == ascending float)
DEVI unsigned key_of(float f) {
  unsigned u = __float_as_uint(f);
  return (u & 0x80000000u) ? ~u : (u | 0x80000000u);
}
DEVI float key_dec(unsigned k) {
  unsigned u = (k & 0x80000000u) ? (k & 0x7fffffffu) : ~k;
  return __uint_as_float(u);
}

// ---------------- kernel 1: weight relayout for LDS-broadcast consumption ----------------
// wT4[chunk*18432 + cc*2304 + g*144 + j*16 + i] = w[co][ci*9+j]
// with co = g*16+i (g = wave 0..15, i = cout-in-wave), ci = chunk*8+cc.
__global__ void transpose_w(const float* __restrict__ w, float* __restrict__ wT4) {
  int k  = blockIdx.x;   // 0..2303  (ci*9 + j)
  int co = threadIdx.x;  // 0..255
  int ci = k / 9, j = k - ci * 9;
  int chunk = ci >> 3, cc = ci & 7;
  int g = co >> 4, i = co & 15;
  wT4[(size_t)chunk * 18432 + cc * 2304 + g * 144 + j * 16 + i] = w[co * 2304 + k];
}

// ---------------- kernel 2: fused conv3x3+bias+relu then 1x1 obj/delta, ALL levels ----------------
// block = 1024 thr (16 waves). tile = 16x16 px; lane owns 4 CONSECUTIVE rows 4p..4p+3 (p = lane>>4).
// wave w owns couts [16w,16w+16) -> all 256 couts in one pass.
// Patch in LDS is COLUMN-MAJOR [ci][x][y] (y-stride 20, b128-aligned, uniform 8 dwords/bank):
// per cc a lane reads 3 columns x (float4 + float2) = 6 LDS reads (vs 36 scalar), reused across ky.
// Weights per 8-ci chunk staged to LDS, read via wave-uniform ds_read_b128 (broadcast).
// FMA order per accumulator: ci ascending, tap (ky,kx) ascending — bit-identical to ref.
__global__ __launch_bounds__(1024, 4) void conv_fused(
    const float* __restrict__ x0, const float* __restrict__ x1,
    const float* __restrict__ x2, const float* __restrict__ x3,
    const float* __restrict__ x4,
    const float* __restrict__ wT4,
    const float* __restrict__ cb, const float* __restrict__ ow,
    const float* __restrict__ ob, const float* __restrict__ dwt,
    const float* __restrict__ db, float* __restrict__ logits,
    float* __restrict__ deltas)
{
  __shared__ float lds[21312];  // 85.2 KB: patch [0,2880) col-major + weights [2880,21312)
  float* const wlds = lds + 2880;
  const int tid = threadIdx.x;
  const int n = blockIdx.y;
  const int b = blockIdx.x;
  int l = 0;
#pragma unroll
  for (int q = 1; q < 5; ++q) if (b >= c_boff[q]) l = q;
  const int t = b - c_boff[l];
  const int H = c_Hl[l], W = H;
  const int tilesx = 16 >> l;
  const int tx = t & (tilesx - 1), ty = t >> (4 - l);
  const int px0 = tx << 4, py0 = ty << 4;
  const int loff = c_loff[l];
  const float* xin = (l == 0) ? x0 : (l == 1) ? x1 : (l == 2) ? x2 : (l == 3) ? x3 : x4;
  xin += (size_t)n * 256 * H * W;

  const int lane = tid & 63, wv = tid >> 6;      // wv 0..15
  const int px = lane & 15, p = lane >> 4;       // lane owns rows 4p..4p+3, col px

  float acc[64];                                 // [row-slot h 0..3][cout-in-wave 0..15]
#pragma unroll
  for (int i = 0; i < 64; ++i) acc[i] = 0.f;

  for (int ch = 0; ch < 32; ++ch) {              // 32 chunks of 8 input channels
    const int ci0 = ch << 3;
    __syncthreads();
    // stage patch: global reads COALESCED (ci,ry,rx row-major), LDS write TRANSPOSED
    // lds[ci*360 + rx*20 + ry]  (x-stride 20, y in [0,18), pad y=18..19 unused)
    for (int tt = tid; tt < 2592; tt += 1024) {
      int ci = tt / 324, rem = tt - ci * 324;
      int ry = rem / 18, rx = rem - ry * 18;
      int gy = py0 + ry - 1, gx = px0 + rx - 1;
      float v = 0.f;
      if (gy >= 0 && gy < H && gx >= 0 && gx < W)
        v = xin[((size_t)(ci0 + ci) * H + gy) * W + gx];
      lds[ci * 360 + rx * 20 + ry] = v;
    }
    // stage this chunk's weights: flat 18432 dwords, coalesced float4
    {
      const float4* wg = (const float4*)(wT4 + (size_t)ch * 18432);
      float4* wl = (float4*)wlds;
      for (int tt = tid; tt < 4608; tt += 1024) wl[tt] = wg[tt];
    }
    __syncthreads();
#pragma unroll 1
    for (int cc = 0; cc < 8; ++cc) {
      const float* wr = wlds + cc * 2304 + wv * 144;   // wave-uniform base -> broadcast reads
      const int pb = cc * 360 + px * 20 + (p << 2);    // dword index, multiple of 4 -> aligned
      // 18 patch floats: columns px, px+1, px+2; rows 4p..4p+5 each (float4 + float2)
      float c0[6], c1[6], c2[6];
      *(float4*)&c0[0] = *(const float4*)&lds[pb +  0];
      *(float2*)&c0[4] = *(const float2*)&lds[pb +  4];
      *(float4*)&c1[0] = *(const float4*)&lds[pb + 20];
      *(float2*)&c1[4] = *(const float2*)&lds[pb + 24];
      *(float4*)&c2[0] = *(const float4*)&lds[pb + 40];
      *(float2*)&c2[4] = *(const float2*)&lds[pb + 44];
#pragma unroll
      for (int ky = 0; ky < 3; ++ky) {
#pragma unroll
        for (int kx = 0; kx < 3; ++kx) {
          const float* wt = wr + (ky * 3 + kx) * 16;
          const float4 wa = *(const float4*)(wt + 0);
          const float4 wb = *(const float4*)(wt + 4);
          const float4 wc = *(const float4*)(wt + 8);
          const float4 wd = *(const float4*)(wt + 12);
          const float v0 = (kx == 0) ? c0[ky + 0] : (kx == 1) ? c1[ky + 0] : c2[ky + 0];
          const float v1 = (kx == 0) ? c0[ky + 1] : (kx == 1) ? c1[ky + 1] : c2[ky + 1];
          const float v2 = (kx == 0) ? c0[ky + 2] : (kx == 1) ? c1[ky + 2] : c2[ky + 2];
          const float v3 = (kx == 0) ? c0[ky + 3] : (kx == 1) ? c1[ky + 3] : c2[ky + 3];
          acc[ 0] = fmaf(wa.x, v0, acc[ 0]); acc[ 1] = fmaf(wa.y, v0, acc[ 1]);
          acc[ 2] = fmaf(wa.z, v0, acc[ 2]); acc[ 3] = fmaf(wa.w, v0, acc[ 3]);
          acc[ 4] = fmaf(wb.x, v0, acc[ 4]); acc[ 5] = fmaf(wb.y, v0, acc[ 5]);
          acc[ 6] = fmaf(wb.z, v0, acc[ 6]); acc[ 7] = fmaf(wb.w, v0, acc[ 7]);
          acc[ 8] = fmaf(wc.x, v0, acc[ 8]); acc[ 9] = fmaf(wc.y, v0, acc[ 9]);
          acc[10] = fmaf(wc.z, v0, acc[10]); acc[11] = fmaf(wc.w, v0, acc[11]);
          acc[12] = fmaf(wd.x, v0, acc[12]); acc[13] = fmaf(wd.y, v0, acc[13]);
          acc[14] = fmaf(wd.z, v0, acc[14]); acc[15] = fmaf(wd.w, v0, acc[15]);
          acc[16] = fmaf(wa.x, v1, acc[16]); acc[17] = fmaf(wa.y, v1, acc[17]);
          acc[18] = fmaf(wa.z, v1, acc[18]); acc[19] = fmaf(wa.w, v1, acc[19]);
          acc[20] = fmaf(wb.x, v1, acc[20]); acc[21] = fmaf(wb.y, v1, acc[21]);
          acc[22] = fmaf(wb.z, v1, acc[22]); acc[23] = fmaf(wb.w, v1, acc[23]);
          acc[24] = fmaf(wc.x, v1, acc[24]); acc[25] = fmaf(wc.y, v1, acc[25]);
          acc[26] = fmaf(wc.z, v1, acc[26]); acc[27] = fmaf(wc.w, v1, acc[27]);
          acc[28] = fmaf(wd.x, v1, acc[28]); acc[29] = fmaf(wd.y, v1, acc[29]);
          acc[30] = fmaf(wd.z, v1, acc[30]); acc[31] = fmaf(wd.w, v1, acc[31]);
          acc[32] = fmaf(wa.x, v2, acc[32]); acc[33] = fmaf(wa.y, v2, acc[33]);
          acc[34] = fmaf(wa.z, v2, acc[34]); acc[35] = fmaf(wa.w, v2, acc[35]);
          acc[36] = fmaf(wb.x, v2, acc[36]); acc[37] = fmaf(wb.y, v2, acc[37]);
          acc[38] = fmaf(wb.z, v2, acc[38]); acc[39] = fmaf(wb.w, v2, acc[39]);
          acc[40] = fmaf(wc.x, v2, acc[40]); acc[41] = fmaf(wc.y, v2, acc[41]);
          acc[42] = fmaf(wc.z, v2, acc[42]); acc[43] = fmaf(wc.w, v2, acc[43]);
          acc[44] = fmaf(wd.x, v2, acc[44]); acc[45] = fmaf(wd.y, v2, acc[45]);
          acc[46] = fmaf(wd.z, v2, acc[46]); acc[47] = fmaf(wd.w, v2, acc[47]);
          acc[48] = fmaf(wa.x, v3, acc[48]); acc[49] = fmaf(wa.y, v3, acc[49]);
          acc[50] = fmaf(wa.z, v3, acc[50]); acc[51] = fmaf(wa.w, v3, acc[51]);
          acc[52] = fmaf(wb.x, v3, acc[52]); acc[53] = fmaf(wb.y, v3, acc[53]);
          acc[54] = fmaf(wb.z, v3, acc[54]); acc[55] = fmaf(wb.w, v3, acc[55]);
          acc[56] = fmaf(wc.x, v3, acc[56]); acc[57] = fmaf(wc.y, v3, acc[57]);
          acc[58] = fmaf(wc.z, v3, acc[58]); acc[59] = fmaf(wc.w, v3, acc[59]);
          acc[60] = fmaf(wd.x, v3, acc[60]); acc[61] = fmaf(wd.y, v3, acc[61]);
          acc[62] = fmaf(wd.z, v3, acc[62]); acc[63] = fmaf(wd.w, v3, acc[63]);
        }
      }
    }
  }

  // epilogue: bias+relu + partial 1x1 convs (3 obj + 12 delta) over this wave's 16 ch,
  // cross-wave reduce in fixed wave order (= channel order 0..255) -> deterministic.
  // pass h: thread (px,p) holds pixel (px, 4p+h).
  const int co0 = __builtin_amdgcn_readfirstlane(wv << 4);
#pragma unroll
  for (int h = 0; h < 4; ++h) {
    float part[15];
#pragma unroll
    for (int f = 0; f < 15; ++f) part[f] = 0.f;
#pragma unroll
    for (int i = 0; i < 16; ++i) {
      float tv = fmaxf(acc[h * 16 + i] + cb[co0 + i], 0.f);
#pragma unroll
      for (int f = 0; f < 3; ++f)  part[f]     = fmaf(tv, ow[f * 256 + co0 + i],  part[f]);
#pragma unroll
      for (int f = 0; f < 12; ++f) part[3 + f] = fmaf(tv, dwt[f * 256 + co0 + i], part[3 + f]);
    }
    __syncthreads();
#pragma unroll
    for (int f = 0; f < 15; ++f) lds[wv * 960 + f * 64 + lane] = part[f];
    __syncthreads();
    for (int tt = tid; tt < 960; tt += 1024) {
      float s = 0.f;
#pragma unroll
      for (int w2 = 0; w2 < 16; ++w2) s += lds[w2 * 960 + tt];  // fixed order: deterministic
      int f = tt >> 6, pp = tt & 63;
      int gx = px0 + (pp & 15), gy = py0 + ((pp >> 4) << 2) + h;
      int cell = gy * W + gx;
      if (f < 3) {
        logits[(size_t)n * S_TOT + loff + cell * 3 + f] = s + ob[f];
      } else {
        int chn = f - 3, a = chn >> 2, c = chn & 3;
        deltas[(((size_t)n * S_TOT + loff + cell * 3 + a) << 2) + c] = s + db[chn];
      }
    }
  }
}

// ---------------- kernel 3: exact top-K + box decode per (image, level) ----------------
__global__ __launch_bounds__(1024) void topk_kernel(
    const float* __restrict__ logits, const float* __restrict__ deltas,
    float* __restrict__ selscore, float* __restrict__ selbox,
    unsigned* __restrict__ selvalid)
{
  const int tid = threadIdx.x;
  const int nl = blockIdx.x, n = nl / 5, l = nl % 5;
  const int Sl = c_S[l], loff = c_loff[l], Kl = c_K[l], Wl = c_Wl[l], strl = c_str[l];
  const float* sc = logits + (size_t)n * S_TOT + loff;

  __shared__ unsigned hist[256];
  __shared__ unsigned sh_prefix, sh_need, s_base, s_cb;
  __shared__ unsigned waveTot[16], waveOff[16];
  __shared__ unsigned long long sortbuf[1024];

  // phase 1: 4-pass radix histogram -> exact Kl-th largest key
  unsigned prefix = 0, need = (unsigned)Kl;
  for (int p = 0; p < 4; ++p) {
    for (int i = tid; i < 256; i += 1024) hist[i] = 0;
    __syncthreads();
    const int shift = 24 - p * 8;
    for (int i = tid; i < Sl; i += 1024) {
      unsigned k = key_of(sc[i]);
      if (p == 0 || (k >> (shift + 8)) == prefix)
        atomicAdd(&hist[(k >> shift) & 255u], 1u);
    }
    __syncthreads();
    if (tid == 0) {
      unsigned cum = 0;
      for (int b = 255; b >= 0; --b) {
        unsigned c = hist[b];
        if (cum + c >= need) { sh_prefix = (prefix << 8) | (unsigned)b; sh_need = need - cum; break; }
        cum += c;
      }
    }
    __syncthreads();
    prefix = sh_prefix; need = sh_need;
    __syncthreads();
  }
  const unsigned Tkey = prefix;

  // phase 2: stable compaction (strictly-greater, then equals capped) -> exactly Kl entries
  if (tid == 0) s_base = 0;
  __syncthreads();
  for (int pass = 0; pass < 2; ++pass) {
    for (int st = 0; st < Sl; st += 1024) {
      const int i = st + tid;
      bool flag = false; unsigned k = 0;
      if (i < Sl) {
        k = key_of(sc[i]);
        flag = (pass == 0) ? (k > Tkey) : (k == Tkey);
      }
      unsigned long long m = __ballot(flag);
      const int lane = tid & 63, w = tid >> 6;
      unsigned mypre = (unsigned)__popcll(m & ((1ull << lane) - 1ull));
      if (lane == 0) waveTot[w] = (unsigned)__popcll(m);
      __syncthreads();
      if (tid == 0) {
        unsigned ss = 0;
        for (int q = 0; q < 16; ++q) { waveOff[q] = ss; ss += waveTot[q]; }
        s_cb = s_base; s_base += ss;
      }
      __syncthreads();
      if (flag) {
        unsigned pos = s_cb + waveOff[w] + mypre;
        if (pos < (unsigned)Kl)
          sortbuf[pos] = (((unsigned long long)k) << 32) |
                         (unsigned long long)(0xFFFFFFFFu - (unsigned)i);
      }
      __syncthreads();
    }
  }
  if (tid >= Kl) sortbuf[tid] = (unsigned long long)(0xFFFFFFFFu - (unsigned)tid); // pads: key 0
  __syncthreads();

  // phase 3: bitonic sort of 1024 u64, descending (key desc, idx asc via ~idx)
  for (int k2 = 2; k2 <= 1024; k2 <<= 1) {
    for (int j = k2 >> 1; j > 0; j >>= 1) {
      const int i = tid, ixj = i ^ j;
      if (ixj > i) {
        unsigned long long a = sortbuf[i], b = sortbuf[ixj];
        const bool desc = (i & k2) == 0;
        if (desc ? (a < b) : (a > b)) { sortbuf[i] = b; sortbuf[ixj] = a; }
      }
      __syncthreads();
    }
  }

  // phase 4: decode boxes (anchors in f64 to bit-match np reference)
  const int r = tid;
  const int o = nl * 1024 + r;
  if (r < Kl) {
    unsigned long long v = sortbuf[r];
    unsigned k = (unsigned)(v >> 32);
    unsigned ai = 0xFFFFFFFFu - (unsigned)(v & 0xFFFFFFFFull);
    float score = key_dec(k);
    int cell = (int)(ai / 3u), a = (int)(ai % 3u);
    int xg = cell % Wl, yg = cell / Wl;
    double rr = c_rat[a], sz = c_sz[l];
    double wsd = sqrt(sz * sz / rr);
    double hw = 0.5 * wsd, hh = 0.5 * wsd * rr;
    double xs = (double)(xg * strl), ys = (double)(yg * strl);
    float a0 = (float)(xs - hw), a1 = (float)(ys - hh);
    float a2 = (float)(xs + hw), a3 = (float)(ys + hh);
    const float* dp = deltas + (((size_t)n * S_TOT + loff + ai) << 2);
    float dx = dp[0], dy = dp[1], dw_ = dp[2], dh_ = dp[3];
    float aw = a2 - a0, ah = a3 - a1;
    float cx = a0 + 0.5f * aw, cy = a1 + 0.5f * ah;
    dw_ = fminf(dw_, (float)SCLD); dh_ = fminf(dh_, (float)SCLD);
    float pcx = dx * aw + cx, pcy = dy * ah + cy;
    float pw = expf(dw_) * aw, ph = expf(dh_) * ah;
    float b0 = fminf(fmaxf(pcx - 0.5f * pw, 0.f), 1024.f);
    float b1 = fminf(fmaxf(pcy - 0.5f * ph, 0.f), 1024.f);
    float b2 = fminf(fmaxf(pcx + 0.5f * pw, 0.f), 1024.f);
    float b3 = fminf(fmaxf(pcy + 0.5f * ph, 0.f), 1024.f);
    unsigned valid = ((b2 - b0) > 0.f && (b3 - b1) > 0.f) ? 1u : 0u;
    selscore[o] = score;
    selbox[o * 4 + 0] = b0; selbox[o * 4 + 1] = b1;
    selbox[o * 4 + 2] = b2; selbox[o * 4 + 3] = b3;
    selvalid[o] = valid;
  } else {
    selscore[o] = -1e9f;
    selbox[o * 4 + 0] = 0.f; selbox[o * 4 + 1] = 0.f;
    selbox[o * 4 + 2] = 0.f; selbox[o * 4 + 3] = 0.f;
    selvalid[o] = 0u;
  }
}

// ---------------- kernel 4: NMS suppression bitmask matrix ----------------
__global__ __launch_bounds__(256) void nms_sup(
    const float* __restrict__ selbox, unsigned long long* __restrict__ sup)
{
  int gid = blockIdx.x * 256 + threadIdx.x;  // 10 * 1024 * 16
  int w = gid & 15, i = (gid >> 4) & 1023, nl = gid >> 14;
  if (nl >= 10) return;
  int l = nl % 5, Kl = c_K[l];
  unsigned long long bits = 0;
  if (i < Kl) {
    const float* bi = selbox + (size_t)(nl * 1024 + i) * 4;
    float x0 = bi[0], y0 = bi[1], x1 = bi[2], y1 = bi[3];
    float ar = (x1 - x0) * (y1 - y0);
    int jlo = w * 64; if (jlo < i + 1) jlo = i + 1;
    int jhi = w * 64 + 64; if (jhi > Kl) jhi = Kl;
    for (int j = jlo; j < jhi; ++j) {
      const float* bj = selbox + (size_t)(nl * 1024 + j) * 4;
      float u0 = fmaxf(x0, bj[0]), v0 = fmaxf(y0, bj[1]);
      float u1 = fminf(x1, bj[2]), v1 = fminf(y1, bj[3]);
      float iw = fmaxf(u1 - u0, 0.f), ih = fmaxf(v1 - v0, 0.f);
      float inter = iw * ih;
      float aj = (bj[2] - bj[0]) * (bj[3] - bj[1]);
      float iou = inter / fmaxf(ar + aj - inter, 1e-9f);
      if (iou > 0.7f) bits |= 1ull << (j - w * 64);
    }
  }
  sup[(size_t)(nl * 1024 + i) * 16 + w] = bits;
}

// ---------------- kernel 5: sequential greedy NMS reduce (1 wave / (n,l)) ----------------
__global__ __launch_bounds__(64) void nms_reduce(
    const unsigned* __restrict__ selvalid, const unsigned long long* __restrict__ sup,
    const float* __restrict__ selscore, float* __restrict__ scnms)
{
  const int nl = blockIdx.x, tid = threadIdx.x;
  const int l = nl % 5, Kl = c_K[l];
  unsigned long long keep = 0;
  if (tid < 16) {
    for (int t = 0; t < 64; ++t) {
      int r = tid * 64 + t;
      if (r < Kl && selvalid[nl * 1024 + r]) keep |= 1ull << t;
    }
  }
  const unsigned long long* srow = sup + (size_t)nl * 1024 * 16;
  unsigned long long rowA = (tid < 16) ? srow[(size_t)0 * 16 + tid] : 0;
  unsigned long long rowB = (tid < 16 && Kl > 1) ? srow[(size_t)1 * 16 + tid] : 0;
  for (int i = 0; i < Kl; i += 2) {   // Kl is even (1000 / 768)
    unsigned long long kw = __shfl(keep, i >> 6);
    unsigned long long cur = rowA;
    rowA = (tid < 16 && i + 2 < Kl) ? srow[(size_t)(i + 2) * 16 + tid] : 0;
    if (((kw >> (i & 63)) & 1ull) && tid < 16) keep &= ~cur;
    kw = __shfl(keep, (i + 1) >> 6);
    cur = rowB;
    rowB = (tid < 16 && i + 3 < Kl) ? srow[(size_t)(i + 3) * 16 + tid] : 0;
    if (((kw >> ((i + 1) & 63)) & 1ull) && tid < 16) keep &= ~cur;
  }
  for (int r = tid; r < 1024; r += 64) {
    unsigned long long wv = __shfl(keep, r >> 6);
    bool kp = (r < Kl) && ((wv >> (r & 63)) & 1ull);
    scnms[nl * 1024 + r] = kp ? selscore[nl * 1024 + r] : -1e9f;
  }
}

// ---------------- kernel 6: final per-image top-1000 of 4768 + output ----------------
DEVI float cand_score(const float* scnms, int n, int g) {
  int l = g / 1000;               // g < 4768 -> l in [0,4]
  int r = g - l * 1000;
  return scnms[((n * 5 + l) << 10) + r];
}

__global__ __launch_bounds__(1024) void final_topk(
    const float* __restrict__ scnms, const float* __restrict__ selbox,
    float* __restrict__ out)
{
  const int tid = threadIdx.x;
  const int n = blockIdx.x;
  const int S = 4768;

  __shared__ unsigned hist[256];
  __shared__ unsigned sh_prefix, sh_need, s_base, s_cb;
  __shared__ unsigned waveTot[16], waveOff[16];
  __shared__ unsigned long long sortbuf[1024];

  unsigned prefix = 0, need = 1000;
  for (int p = 0; p < 4; ++p) {
    for (int i = tid; i < 256; i += 1024) hist[i] = 0;
    __syncthreads();
    const int shift = 24 - p * 8;
    for (int i = tid; i < S; i += 1024) {
      unsigned k = key_of(cand_score(scnms, n, i));
      if (p == 0 || (k >> (shift + 8)) == prefix)
        atomicAdd(&hist[(k >> shift) & 255u], 1u);
    }
    __syncthreads();
    if (tid == 0) {
      unsigned cum = 0;
      for (int b = 255; b >= 0; --b) {
        unsigned c = hist[b];
        if (cum + c >= need) { sh_prefix = (prefix << 8) | (unsigned)b; sh_need = need - cum; break; }
        cum += c;
      }
    }
    __syncthreads();
    prefix = sh_prefix; need = sh_need;
    __syncthreads();
  }
  const unsigned Tkey = prefix;

  if (tid == 0) s_base = 0;
  __syncthreads();
  for (int pass = 0; pass < 2; ++pass) {
    for (int st = 0; st < S; st += 1024) {
      const int i = st + tid;
      bool flag = false; unsigned k = 0;
      if (i < S) {
        k = key_of(cand_score(scnms, n, i));
        flag = (pass == 0) ? (k > Tkey) : (k == Tkey);
      }
      unsigned long long m = __ballot(flag);
      const int lane = tid & 63, w = tid >> 6;
      unsigned mypre = (unsigned)__popcll(m & ((1ull << lane) - 1ull));
      if (lane == 0) waveTot[w] = (unsigned)__popcll(m);
      __syncthreads();
      if (tid == 0) {
        unsigned ss = 0;
        for (int q = 0; q < 16; ++q) { waveOff[q] = ss; ss += waveTot[q]; }
        s_cb = s_base; s_base += ss;
      }
      __syncthreads();
      if (flag) {
        unsigned pos = s_cb + waveOff[w] + mypre;
        if (pos < 1000u)
          sortbuf[pos] = (((unsigned long long)k) << 32) |
                         (unsigned long long)(0xFFFFFFFFu - (unsigned)i);
      }
      __syncthreads();
    }
  }
  if (tid >= 1000) sortbuf[tid] = (unsigned long long)(0xFFFFFFFFu - (unsigned)tid);
  __syncthreads();

  for (int k2 = 2; k2 <= 1024; k2 <<= 1) {
    for (int j = k2 >> 1; j > 0; j >>= 1) {
      const int i = tid, ixj = i ^ j;
      if (ixj > i) {
        unsigned long long a = sortbuf[i], b = sortbuf[ixj];
        const bool desc = (i & k2) == 0;
        if (desc ? (a < b) : (a > b)) { sortbuf[i] = b; sortbuf[ixj] = a; }
      }
      __syncthreads();
    }
  }

  if (tid < 1000) {
    unsigned long long v = sortbuf[tid];
    unsigned k = (unsigned)(v >> 32);
    int g = (int)(0xFFFFFFFFu - (unsigned)(v & 0xFFFFFFFFull));
    int l = g / 1000, r = g - l * 1000;
    const float* b = selbox + ((size_t)((n * 5 + l) * 1024 + r)) * 4;
    size_t ob_ = ((size_t)n * 1000 + tid) * 4;
    out[ob_ + 0] = b[0]; out[ob_ + 1] = b[1];
    out[ob_ + 2] = b[2]; out[ob_ + 3] = b[3];
    out[8000 + n * 1000 + tid] = key_dec(k);
  }
}

// ---------------- host launcher ----------------
extern "C" void kernel_launch(void* const* d_in, const int* in_sizes, int n_in,
                              void* d_out, int out_size, void* d_ws, size_t ws_size,
                              hipStream_t stream)
{
  const float* feats[5];
  for (int i = 0; i < 5; ++i) feats[i] = (const float*)d_in[i];
  const float* conv_w  = (const float*)d_in[5];
  const float* conv_b  = (const float*)d_in[6];
  const float* obj_w   = (const float*)d_in[7];
  const float* obj_b   = (const float*)d_in[8];
  const float* delta_w = (const float*)d_in[9];
  const float* delta_b = (const float*)d_in[10];

  char* wsp = (char*)d_ws;
  float* wT4      = (float*)wsp;  wsp += (size_t)2304 * 256 * 4;     // 2.36 MB
  float* logits   = (float*)wsp;  wsp += (size_t)NIMG * S_TOT * 4;   // 2.10 MB
  float* deltas   = (float*)wsp;  wsp += (size_t)NIMG * S_TOT * 16;  // 8.38 MB
  float* selscore = (float*)wsp;  wsp += (size_t)10 * 1024 * 4;
  float* selbox   = (float*)wsp;  wsp += (size_t)10 * 1024 * 16;
  unsigned* selvalid = (unsigned*)wsp; wsp += (size_t)10 * 1024 * 4;
  float* scnms    = (float*)wsp;  wsp += (size_t)10 * 1024 * 4;
  unsigned long long* sup = (unsigned long long*)wsp;
  wsp += (size_t)10 * 1024 * 16 * 8;                                 // 1.31 MB

  transpose_w<<<dim3(2304), dim3(256), 0, stream>>>(conv_w, wT4);

  conv_fused<<<dim3(341, NIMG), dim3(1024), 0, stream>>>(
      feats[0], feats[1], feats[2], feats[3], feats[4],
      wT4, conv_b, obj_w, obj_b, delta_w, delta_b, logits, deltas);

  topk_kernel<<<dim3(10), dim3(1024), 0, stream>>>(logits, deltas,
                                                   selscore, selbox, selvalid);
  nms_sup<<<dim3(640), dim3(256), 0, stream>>>(selbox, sup);
  nms_reduce<<<dim3(10), dim3(64), 0, stream>>>(selvalid, sup, selscore, scnms);
  final_topk<<<dim3(NIMG), dim3(1024), 0, stream>>>(scnms, selbox, (float*)d_out);
}